// Round 13
// baseline (843.750 us; speedup 1.0000x reference)
//
#include <hip/hip_runtime.h>
#include <math.h>

#define TOKS 8192
#define HD 1024
#define ID 2048
#define NE 8

typedef __bf16 bf16_t;
typedef __bf16 bf16x8 __attribute__((ext_vector_type(8)));
typedef float f32x4 __attribute__((ext_vector_type(4)));

// async global->LDS, 16 bytes per lane. LDS dest: wave-uniform base + lane*16.
#define GLOAD(gp, lp)                                                \
  __builtin_amdgcn_global_load_lds(                                  \
      (const __attribute__((address_space(1))) void*)(gp),           \
      (__attribute__((address_space(3))) void*)(lp), 16, 0, 0)

// branch-free erf-GELU (A&S 7.1.26, |eps|<=1.5e-7 — invisible under bf16 2^-9
// rounding). r11-verified: absmax unchanged vs libm erff.
__device__ __forceinline__ float gelu_exact(float v) {
  const float u = v * 0.70710678118654752f;
  const float a = fabsf(u);
  const float t = 1.f / (1.f + 0.3275911f * a);
  const float poly =
      t * (0.254829592f +
           t * (-0.284496736f +
                t * (1.421413741f + t * (-1.453152027f + t * 1.061405429f))));
  float er = 1.f - poly * __expf(-a * a);
  er = copysignf(er, u);
  return 0.5f * v * (1.f + er);
}

// ---------------- workspace layout (bytes) ----------------
#define WS_COUNTS 0
#define WS_OFFSETS 32
#define WS_BTOK 128
#define WS_BW (128 + 65536)
#define WS_TE (128 + 2 * 65536)
#define WS_TW (128 + 3 * 65536)
#define WS_WL 263168ull
#define WS_POS 274432ull                      // pos_of   [16384] int (64 KB)
#define WS_RANK 339968ull                     // rank_of  [16384] int (64 KB)
#define WS_BLKC 405504ull                     // blk_cnt  [1024][8] int (32 KB)
#define WS_BLKB 438272ull                     // blk_base [1024][8] int (32 KB)
#define WS_XB 524288ull                       // bf16 x  [8192][1024]  = 16.78 MB
#define WS_H1 (WS_XB + 16777216ull)           // bf16 h1 [16384][2048] = 67.1 MB
#define WS_WT (WS_H1 + 67108864ull)           // bf16 WT (W1T then W2T) = 33.55 MB
#define WS_Y (WS_WT + 33554432ull)            // bf16 y  [16384][1024] = 33.55 MB (ends ~151.5 MB)

#define MAXWL 144
#define BM 128  // m-tile (rows of token bucket) — r5/r9-verified best geometry
#define GB (TOKS / 8)  // gate blocks = 1024

// ---------------- gating + fused convert + fused histogram (r12) ----------------
__global__ __launch_bounds__(256) void gate_kernel(const float* __restrict__ x,
                                                   const float* __restrict__ Wg,
                                                   bf16_t* __restrict__ xb,
                                                   int* __restrict__ tok_e,
                                                   float* __restrict__ tok_w,
                                                   int* __restrict__ rank_of,
                                                   int* __restrict__ blk_cnt) {
  __shared__ float WgT[HD * NE];  // straight copy of Wg (32 KB)
  __shared__ int cnt[NE];
  const int tid = threadIdx.x;
#pragma unroll
  for (int i = 0; i < NE * HD / (256 * 4); ++i) {  // 8 float4 per thread
    const int k = i * 256 + tid;
    ((float4*)WgT)[k] = ((const float4*)Wg)[k];
  }
  if (tid < NE) cnt[tid] = 0;
  __syncthreads();
  const int wv = tid >> 6;
  const int lane = tid & 63;
#pragma unroll
  for (int s = 0; s < 2; ++s) {
    const int t = blockIdx.x * 8 + wv * 2 + s;
    const float* xrow = x + (size_t)t * HD;
    bf16_t* xbrow = xb + (size_t)t * HD;
    float acc[NE];
#pragma unroll
    for (int e = 0; e < NE; ++e) acc[e] = 0.f;
#pragma unroll
    for (int i = 0; i < 16; ++i) {
      const int h = i * 64 + lane;
      const float xv = xrow[h];
      xbrow[h] = (bf16_t)xv;  // fused convert
      const float4 w0 = *(const float4*)(WgT + h * NE);
      const float4 w1 = *(const float4*)(WgT + h * NE + 4);
      acc[0] += xv * w0.x;
      acc[1] += xv * w0.y;
      acc[2] += xv * w0.z;
      acc[3] += xv * w0.w;
      acc[4] += xv * w1.x;
      acc[5] += xv * w1.y;
      acc[6] += xv * w1.z;
      acc[7] += xv * w1.w;
    }
#pragma unroll
    for (int off = 32; off >= 1; off >>= 1) {
#pragma unroll
      for (int e = 0; e < NE; ++e) acc[e] += __shfl_xor(acc[e], off);
    }
    if (lane == 0) {
      int i1 = 0;
      float l1 = acc[0];
#pragma unroll
      for (int e = 1; e < NE; ++e)
        if (acc[e] > l1) { l1 = acc[e]; i1 = e; }
      int i2 = -1;
      float l2 = -3.4e38f;
#pragma unroll
      for (int e = 0; e < NE; ++e)
        if (e != i1 && acc[e] > l2) { l2 = acc[e]; i2 = e; }
      const float q = expf(l2 - l1);
      const float w1 = 1.f / (1.f + q);
      tok_e[2 * t] = i1;
      tok_e[2 * t + 1] = i2;
      tok_w[2 * t] = w1;
      tok_w[2 * t + 1] = q * w1;
      rank_of[2 * t] = atomicAdd(&cnt[i1], 1);
      rank_of[2 * t + 1] = atomicAdd(&cnt[i2], 1);
    }
  }
  __syncthreads();
  if (tid < NE) blk_cnt[blockIdx.x * NE + tid] = cnt[tid];
}

// ---------------- scan: one wave; 16 gate-blocks per lane + 64-wide prefix ----
__global__ void scan_kernel(const int* __restrict__ blk_cnt, int* __restrict__ counts,
                            int* __restrict__ offsets, int* __restrict__ blk_base,
                            int* __restrict__ wl_e, int* __restrict__ wl_m,
                            int* __restrict__ n_work) {
  const int b = threadIdx.x;  // 0..63; handles gate-blocks b*16 .. b*16+15
  int sum[NE], pre[NE], tot[NE];
#pragma unroll
  for (int e = 0; e < NE; ++e) {
    int s = 0;
    for (int j = 0; j < 16; ++j) s += blk_cnt[(b * 16 + j) * NE + e];
    sum[e] = s;
  }
#pragma unroll
  for (int e = 0; e < NE; ++e) {
    int v = sum[e];
#pragma unroll
    for (int off = 1; off < 64; off <<= 1) {
      const int u = __shfl_up(v, off);
      if (b >= off) v += u;
    }
    pre[e] = v - sum[e];        // exclusive prefix over lanes
    tot[e] = __shfl(v, 63);     // expert total
  }
  int off_[NE];
  int s = 0;
#pragma unroll
  for (int e = 0; e < NE; ++e) {
    off_[e] = s;
    s += tot[e];
  }
#pragma unroll
  for (int e = 0; e < NE; ++e) {
    int run = off_[e] + pre[e];
    for (int j = 0; j < 16; ++j) {
      blk_base[(b * 16 + j) * NE + e] = run;
      run += blk_cnt[(b * 16 + j) * NE + e];
    }
  }
  if (b == 0) {
    int idx = 0;
    for (int e = 0; e < NE; ++e) {
      counts[e] = tot[e];
      offsets[e] = off_[e];
      for (int m = 0; m < tot[e] && idx < MAXWL; m += BM) {
        wl_e[idx] = e;
        wl_m[idx] = m;
        ++idx;
      }
    }
    *n_work = idx;
  }
}

// ---------------- scatter: pure gather — pos = blk_base + rank ----
__global__ __launch_bounds__(256) void scatter_kernel(const int* __restrict__ tok_e,
                                                      const float* __restrict__ tok_w,
                                                      const int* __restrict__ blk_base,
                                                      const int* __restrict__ rank_of,
                                                      int* __restrict__ bucket_tok,
                                                      float* __restrict__ bucket_w,
                                                      int* __restrict__ pos_of) {
  const int idx = blockIdx.x * 256 + threadIdx.x;
  const int e = tok_e[idx];
  const int gb = idx >> 4;  // 16 picks per gate-block
  const int pos = blk_base[gb * NE + e] + rank_of[idx];
  bucket_tok[pos] = idx >> 1;
  bucket_w[pos] = tok_w[idx];
  pos_of[idx] = pos;
}

// ---------------- transpose+convert: src [E][K][N] f32 -> dst [E][N][K] bf16 ----
__global__ __launch_bounds__(256) void transpose_convert_kernel(const float* __restrict__ src,
                                                                bf16_t* __restrict__ dst, int K,
                                                                int N) {
  __shared__ float tile[64][65];
  const int e = blockIdx.z;
  const int k0 = blockIdx.x * 64;
  const int n0 = blockIdx.y * 64;
  const float* s = src + (size_t)e * K * N;
  bf16_t* d = dst + (size_t)e * K * N;
  const int t = threadIdx.x;
  const int c4 = (t & 15) * 4;
  const int rr = t >> 4;  // 0..15
#pragma unroll
  for (int p = 0; p < 4; ++p) {
    const int r = p * 16 + rr;
    const float4 v = *(const float4*)(s + (size_t)(k0 + r) * N + n0 + c4);
    tile[r][c4] = v.x;
    tile[r][c4 + 1] = v.y;
    tile[r][c4 + 2] = v.z;
    tile[r][c4 + 3] = v.w;
  }
  __syncthreads();
  const int kc = t & 7;
  const int nb = t >> 3;
#pragma unroll
  for (int p = 0; p < 2; ++p) {
    const int n = p * 32 + nb;
    bf16_t o[8];
#pragma unroll
    for (int j = 0; j < 8; ++j) o[j] = (bf16_t)tile[kc * 8 + j][n];
    *(uint4*)(d + (size_t)(n0 + n) * K + k0 + kc * 8) = *(uint4*)o;
  }
}

// ---------------- expert GEMMs: 128x128 tile, 2-buffer, 5 blocks/CU ----------------
// r12 post-mortem: 3-buffer counted-vmcnt (48KB LDS) caps residency at 3
// blocks/CU; per-block-iter ~3435 cyc / 3 = 1145 cyc/iter-slot. r1's 2-buffer
// data shows per-block-iter ~4360 but its low occupancy was GRID-depth-capped
// (4 blocks/CU of work), not LDS-capped. At 32KB LDS (2 buffers) 5 blocks fit:
// 4360/5 ~= 870 cyc/iter-slot, above the ~512 LDS-port floor -> TLP beats
// pipeline depth here. Loop = r7/r8-verified single-barrier 2ph: stage-next ->
// ds_read+MFMA -> __syncthreads (implicit vmcnt0+lgkm0 drain).
// launch_bounds(256,5) pins VGPR <= 102 (have 76).

__global__ __launch_bounds__(256, 5) void gemm1_kernel(
    const bf16_t* __restrict__ xb, const bf16_t* __restrict__ W1T, const float* __restrict__ b1,
    const int* __restrict__ counts, const int* __restrict__ offsets,
    const int* __restrict__ bucket_tok, const int* __restrict__ wl_e,
    const int* __restrict__ wl_m, const int* __restrict__ n_work, bf16_t* __restrict__ h1) {
  const int widx = blockIdx.x;
  if (widx >= *n_work) return;
  const int e = wl_e[widx];
  const int m_base = wl_m[widx];
  const int n_e = counts[e];
  const int n_base = blockIdx.y * 128;
  const int off = offsets[e];

  __shared__ bf16_t As[2][128 * 32];  // 8 KB each -> 32 KB total
  __shared__ bf16_t Bs[2][128 * 32];

  const int tid = threadIdx.x;
  const int w = tid >> 6;
  const int lane = tid & 63;
  const int quad = lane >> 4;
  const int lrow = lane & 15;
  const int wm = w >> 1;   // 64-row half
  const int wn = w & 1;    // 64-col half

  const int srow = lane >> 2;                        // 16 rows per GLOAD
  const int kch = (((lane & 3) ^ ((lane >> 4) & 3)) * 8);  // pre-swizzled source chunk
  int r0 = m_base + w * 32 + srow;
  int r1 = r0 + 16;
  if (r0 >= n_e) r0 = n_e - 1;
  if (r1 >= n_e) r1 = n_e - 1;
  const bf16_t* ga0 = xb + (size_t)bucket_tok[off + r0] * HD + kch;
  const bf16_t* ga1 = xb + (size_t)bucket_tok[off + r1] * HD + kch;
  const bf16_t* gb0 = W1T + ((size_t)e * ID + n_base + w * 32 + srow) * HD + kch;
  const bf16_t* gb1 = gb0 + (size_t)16 * HD;
  const int laofs0 = w * 1024 + lane * 8;  // rows w*32.. in [128][32]
  const int laofs1 = laofs0 + 512;         // +16 rows

  f32x4 acc[4][4];
#pragma unroll
  for (int mt = 0; mt < 4; ++mt)
#pragma unroll
    for (int nt = 0; nt < 4; ++nt)
#pragma unroll
      for (int r = 0; r < 4; ++r) acc[mt][nt][r] = 0.f;

  // prologue: stage tile 0 into buffer 0
  GLOAD(ga0, &As[0][laofs0]);
  GLOAD(ga1, &As[0][laofs1]);
  GLOAD(gb0, &Bs[0][laofs0]);
  GLOAD(gb1, &Bs[0][laofs1]);
  __syncthreads();

  const int slot = (quad ^ ((lrow >> 2) & 3)) * 8;
#define NT1 (HD / 32)
  for (int kt = 0; kt < NT1; ++kt) {
    const int cur = kt & 1;
    if (kt + 1 < NT1) {  // stage next tile; HBM latency hides under MFMA
      const int nxt = cur ^ 1;
      const size_t ko = (size_t)(kt + 1) * 32;
      GLOAD(ga0 + ko, &As[nxt][laofs0]);
      GLOAD(ga1 + ko, &As[nxt][laofs1]);
      GLOAD(gb0 + ko, &Bs[nxt][laofs0]);
      GLOAD(gb1 + ko, &Bs[nxt][laofs1]);
    }
    bf16x8 af[4], bfr[4];
#pragma unroll
    for (int i = 0; i < 4; ++i) {
      af[i] = *(const bf16x8*)(&As[cur][(wm * 64 + i * 16 + lrow) * 32 + slot]);
      bfr[i] = *(const bf16x8*)(&Bs[cur][(wn * 64 + i * 16 + lrow) * 32 + slot]);
    }
    __builtin_amdgcn_s_setprio(1);
#pragma unroll
    for (int mt = 0; mt < 4; ++mt)
#pragma unroll
      for (int nt = 0; nt < 4; ++nt)
        acc[mt][nt] =
            __builtin_amdgcn_mfma_f32_16x16x32_bf16(bfr[nt], af[mt], acc[mt][nt], 0, 0, 0);
    __builtin_amdgcn_s_setprio(0);
    __syncthreads();  // drains vmcnt(0)+lgkmcnt(0): next tile staged, reads done
  }

  // C^T epilogue: lane owns token gm = ..+lrow; 4 consecutive cols per (nt).
#pragma unroll
  for (int mt = 0; mt < 4; ++mt) {
    const int gm = m_base + wm * 64 + mt * 16 + lrow;
    if (gm < n_e) {
      bf16_t* orow = h1 + (size_t)(off + gm) * ID;
#pragma unroll
      for (int nt = 0; nt < 4; ++nt) {
        const int gi0 = n_base + wn * 64 + nt * 16 + quad * 4;
        const float4 bb = *(const float4*)(b1 + e * ID + gi0);
        const float bv[4] = {bb.x, bb.y, bb.z, bb.w};
        bf16_t o[4];
#pragma unroll
        for (int r = 0; r < 4; ++r) o[r] = (bf16_t)gelu_exact(acc[mt][nt][r] + bv[r]);
        *(uint2*)(orow + gi0) = *(uint2*)o;
      }
    }
  }
}

// gemm2: identical loop; epilogue stores y[pos] = row + b2 (bf16, no atomics).
__global__ __launch_bounds__(256, 5) void gemm2_kernel(
    const bf16_t* __restrict__ h1, const bf16_t* __restrict__ W2T, const float* __restrict__ b2,
    const int* __restrict__ counts, const int* __restrict__ offsets,
    const int* __restrict__ wl_e, const int* __restrict__ wl_m, const int* __restrict__ n_work,
    bf16_t* __restrict__ y) {
  const int widx = blockIdx.x;
  if (widx >= *n_work) return;
  const int e = wl_e[widx];
  const int m_base = wl_m[widx];
  const int n_e = counts[e];
  const int n_base = blockIdx.y * 128;
  const int off = offsets[e];

  __shared__ bf16_t As[2][128 * 32];
  __shared__ bf16_t Bs[2][128 * 32];

  const int tid = threadIdx.x;
  const int w = tid >> 6;
  const int lane = tid & 63;
  const int quad = lane >> 4;
  const int lrow = lane & 15;
  const int wm = w >> 1;
  const int wn = w & 1;

  const int srow = lane >> 2;
  const int kch = (((lane & 3) ^ ((lane >> 4) & 3)) * 8);
  int r0 = m_base + w * 32 + srow;
  int r1 = r0 + 16;
  if (r0 >= n_e) r0 = n_e - 1;
  if (r1 >= n_e) r1 = n_e - 1;
  const bf16_t* ga0 = h1 + (size_t)(off + r0) * ID + kch;
  const bf16_t* ga1 = h1 + (size_t)(off + r1) * ID + kch;
  const bf16_t* gb0 = W2T + ((size_t)e * HD + n_base + w * 32 + srow) * ID + kch;
  const bf16_t* gb1 = gb0 + (size_t)16 * ID;
  const int laofs0 = w * 1024 + lane * 8;
  const int laofs1 = laofs0 + 512;

  f32x4 acc[4][4];
#pragma unroll
  for (int mt = 0; mt < 4; ++mt)
#pragma unroll
    for (int nt = 0; nt < 4; ++nt)
#pragma unroll
      for (int r = 0; r < 4; ++r) acc[mt][nt][r] = 0.f;

  GLOAD(ga0, &As[0][laofs0]);
  GLOAD(ga1, &As[0][laofs1]);
  GLOAD(gb0, &Bs[0][laofs0]);
  GLOAD(gb1, &Bs[0][laofs1]);
  __syncthreads();

  const int slot = (quad ^ ((lrow >> 2) & 3)) * 8;
#define NT2 (ID / 32)
  for (int kt = 0; kt < NT2; ++kt) {
    const int cur = kt & 1;
    if (kt + 1 < NT2) {
      const int nxt = cur ^ 1;
      const size_t ko = (size_t)(kt + 1) * 32;
      GLOAD(ga0 + ko, &As[nxt][laofs0]);
      GLOAD(ga1 + ko, &As[nxt][laofs1]);
      GLOAD(gb0 + ko, &Bs[nxt][laofs0]);
      GLOAD(gb1 + ko, &Bs[nxt][laofs1]);
    }
    bf16x8 af[4], bfr[4];
#pragma unroll
    for (int i = 0; i < 4; ++i) {
      af[i] = *(const bf16x8*)(&As[cur][(wm * 64 + i * 16 + lrow) * 32 + slot]);
      bfr[i] = *(const bf16x8*)(&Bs[cur][(wn * 64 + i * 16 + lrow) * 32 + slot]);
    }
    __builtin_amdgcn_s_setprio(1);
#pragma unroll
    for (int mt = 0; mt < 4; ++mt)
#pragma unroll
      for (int nt = 0; nt < 4; ++nt)
        acc[mt][nt] =
            __builtin_amdgcn_mfma_f32_16x16x32_bf16(bfr[nt], af[mt], acc[mt][nt], 0, 0, 0);
    __builtin_amdgcn_s_setprio(0);
    __syncthreads();
  }

#pragma unroll
  for (int mt = 0; mt < 4; ++mt) {
    const int gm = m_base + wm * 64 + mt * 16 + lrow;
    if (gm < n_e) {
      bf16_t* orow = y + (size_t)(off + gm) * HD;
#pragma unroll
      for (int nt = 0; nt < 4; ++nt) {
        const int gi0 = n_base + wn * 64 + nt * 16 + quad * 4;
        const float4 bb = *(const float4*)(b2 + e * HD + gi0);
        const float bv[4] = {bb.x, bb.y, bb.z, bb.w};
        bf16_t o[4];
#pragma unroll
        for (int r = 0; r < 4; ++r) o[r] = (bf16_t)(acc[mt][nt][r] + bv[r]);
        *(uint2*)(orow + gi0) = *(uint2*)o;
      }
    }
  }
}

// ---------------- combine: out[t] = w1*y[p1] + w2*y[p2] ----
__global__ __launch_bounds__(256) void combine_kernel(const bf16_t* __restrict__ y,
                                                      const int* __restrict__ pos_of,
                                                      const float* __restrict__ tok_w,
                                                      float* __restrict__ out) {
  const int gid = blockIdx.x * 256 + threadIdx.x;
  const int t = gid >> 7;             // 128 8-wide chunks per token row
  const int c8 = (gid & 127) * 8;
  const int p1 = pos_of[2 * t];
  const int p2 = pos_of[2 * t + 1];
  const float w1 = tok_w[2 * t];
  const float w2 = tok_w[2 * t + 1];
  const bf16x8 a = *(const bf16x8*)(y + (size_t)p1 * HD + c8);
  const bf16x8 b = *(const bf16x8*)(y + (size_t)p2 * HD + c8);
  float* op = out + (size_t)t * HD + c8;
  float ov[8];
#pragma unroll
  for (int j = 0; j < 8; ++j) ov[j] = w1 * (float)a[j] + w2 * (float)b[j];
  *(float4*)op = make_float4(ov[0], ov[1], ov[2], ov[3]);
  *(float4*)(op + 4) = make_float4(ov[4], ov[5], ov[6], ov[7]);
}

extern "C" void kernel_launch(void* const* d_in, const int* in_sizes, int n_in,
                              void* d_out, int out_size, void* d_ws, size_t ws_size,
                              hipStream_t stream) {
  const float* x = (const float*)d_in[0];
  const float* Wg = (const float*)d_in[1];
  const float* W1 = (const float*)d_in[2];
  const float* b1 = (const float*)d_in[3];
  const float* W2 = (const float*)d_in[4];
  const float* b2 = (const float*)d_in[5];
  float* out = (float*)d_out;
  char* ws = (char*)d_ws;

  int* counts = (int*)(ws + WS_COUNTS);
  int* offsets = (int*)(ws + WS_OFFSETS);
  int* bucket_tok = (int*)(ws + WS_BTOK);
  float* bucket_w = (float*)(ws + WS_BW);
  int* tok_e = (int*)(ws + WS_TE);
  float* tok_w = (float*)(ws + WS_TW);
  int* wl_e = (int*)(ws + WS_WL);
  int* wl_m = wl_e + MAXWL;
  int* n_work = wl_m + MAXWL;
  int* pos_of = (int*)(ws + WS_POS);
  int* rank_of = (int*)(ws + WS_RANK);
  int* blk_cnt = (int*)(ws + WS_BLKC);
  int* blk_base = (int*)(ws + WS_BLKB);
  bf16_t* xb = (bf16_t*)(ws + WS_XB);
  bf16_t* h1 = (bf16_t*)(ws + WS_H1);
  bf16_t* WT = (bf16_t*)(ws + WS_WT);
  bf16_t* y = (bf16_t*)(ws + WS_Y);

  gate_kernel<<<GB, 256, 0, stream>>>(x, Wg, xb, tok_e, tok_w, rank_of, blk_cnt);
  scan_kernel<<<1, 64, 0, stream>>>(blk_cnt, counts, offsets, blk_base, wl_e, wl_m, n_work);
  scatter_kernel<<<TOKS * 2 / 256, 256, 0, stream>>>(tok_e, tok_w, blk_base, rank_of,
                                                     bucket_tok, bucket_w, pos_of);
  transpose_convert_kernel<<<dim3(HD / 64, ID / 64, NE), 256, 0, stream>>>(W1, WT, HD, ID);
  gemm1_kernel<<<dim3(MAXWL, ID / 128), 256, 0, stream>>>(xb, WT, b1, counts, offsets, bucket_tok,
                                                          wl_e, wl_m, n_work, h1);
  transpose_convert_kernel<<<dim3(ID / 64, HD / 64, NE), 256, 0, stream>>>(W2, WT, ID, HD);
  gemm2_kernel<<<dim3(MAXWL, HD / 128), 256, 0, stream>>>(h1, WT, b2, counts, offsets, wl_e,
                                                          wl_m, n_work, y);
  combine_kernel<<<TOKS * HD / (256 * 8), 256, 0, stream>>>(y, pos_of, tok_w, out);
}

// Round 14
// 466.205 us; speedup vs baseline: 1.8098x; 1.8098x over previous
//
#include <hip/hip_runtime.h>
#include <math.h>

#define TOKS 8192
#define HD 1024
#define ID 2048
#define NE 8

typedef __bf16 bf16_t;
typedef __bf16 bf16x8 __attribute__((ext_vector_type(8)));
typedef float f32x4 __attribute__((ext_vector_type(4)));

// async global->LDS, 16 bytes per lane. LDS dest: wave-uniform base + lane*16.
#define GLOAD(gp, lp)                                                \
  __builtin_amdgcn_global_load_lds(                                  \
      (const __attribute__((address_space(1))) void*)(gp),           \
      (__attribute__((address_space(3))) void*)(lp), 16, 0, 0)

// branch-free erf-GELU (A&S 7.1.26, |eps|<=1.5e-7 — invisible under bf16 2^-9
// rounding). r11-verified: absmax unchanged vs libm erff.
__device__ __forceinline__ float gelu_exact(float v) {
  const float u = v * 0.70710678118654752f;
  const float a = fabsf(u);
  const float t = 1.f / (1.f + 0.3275911f * a);
  const float poly =
      t * (0.254829592f +
           t * (-0.284496736f +
                t * (1.421413741f + t * (-1.453152027f + t * 1.061405429f))));
  float er = 1.f - poly * __expf(-a * a);
  er = copysignf(er, u);
  return 0.5f * v * (1.f + er);
}

// ---------------- workspace layout (bytes) ----------------
#define WS_COUNTS 0
#define WS_OFFSETS 32
#define WS_BTOK 128
#define WS_BW (128 + 65536)
#define WS_TE (128 + 2 * 65536)
#define WS_TW (128 + 3 * 65536)
#define WS_WL 263168ull
#define WS_POS 274432ull                      // pos_of   [16384] int (64 KB)
#define WS_RANK 339968ull                     // rank_of  [16384] int (64 KB)
#define WS_BLKC 405504ull                     // blk_cnt  [256][8] int (8 KB)
#define WS_XB 524288ull                       // bf16 x  [8192][1024]  = 16.78 MB
#define WS_H1 (WS_XB + 16777216ull)           // bf16 h1 [16384][2048] = 67.1 MB
#define WS_WT (WS_H1 + 67108864ull)           // bf16 WT (W1T then W2T) = 33.55 MB
#define WS_Y (WS_WT + 33554432ull)            // bf16 y  [16384][1024] = 33.55 MB (ends ~151.5 MB)

#define MAXWL 144
#define BM 128      // m-tile (rows of token bucket)
#define GB 256      // gate blocks; 32 tokens each

// ---------------- gating + fused convert + per-block histogram ----------------
// 256 blocks x 32 tokens. Writes tok_e/tok_w/rank_of + blk_cnt[256][8].
__global__ __launch_bounds__(256) void gate_kernel(const float* __restrict__ x,
                                                   const float* __restrict__ Wg,
                                                   bf16_t* __restrict__ xb,
                                                   int* __restrict__ tok_e,
                                                   float* __restrict__ tok_w,
                                                   int* __restrict__ rank_of,
                                                   int* __restrict__ blk_cnt) {
  __shared__ float WgT[HD * NE];  // straight copy of Wg (32 KB)
  __shared__ int cnt[NE];
  const int tid = threadIdx.x;
#pragma unroll
  for (int i = 0; i < NE * HD / (256 * 4); ++i) {  // 8 float4 per thread
    const int k = i * 256 + tid;
    ((float4*)WgT)[k] = ((const float4*)Wg)[k];
  }
  if (tid < NE) cnt[tid] = 0;
  __syncthreads();
  const int wv = tid >> 6;
  const int lane = tid & 63;
#pragma unroll
  for (int s = 0; s < 8; ++s) {
    const int t = blockIdx.x * 32 + wv * 8 + s;
    const float* xrow = x + (size_t)t * HD;
    bf16_t* xbrow = xb + (size_t)t * HD;
    float acc[NE];
#pragma unroll
    for (int e = 0; e < NE; ++e) acc[e] = 0.f;
#pragma unroll
    for (int i = 0; i < 16; ++i) {
      const int h = i * 64 + lane;
      const float xv = xrow[h];
      xbrow[h] = (bf16_t)xv;  // fused convert
      const float4 w0 = *(const float4*)(WgT + h * NE);
      const float4 w1 = *(const float4*)(WgT + h * NE + 4);
      acc[0] += xv * w0.x;
      acc[1] += xv * w0.y;
      acc[2] += xv * w0.z;
      acc[3] += xv * w0.w;
      acc[4] += xv * w1.x;
      acc[5] += xv * w1.y;
      acc[6] += xv * w1.z;
      acc[7] += xv * w1.w;
    }
#pragma unroll
    for (int off = 32; off >= 1; off >>= 1) {
#pragma unroll
      for (int e = 0; e < NE; ++e) acc[e] += __shfl_xor(acc[e], off);
    }
    if (lane == 0) {
      int i1 = 0;
      float l1 = acc[0];
#pragma unroll
      for (int e = 1; e < NE; ++e)
        if (acc[e] > l1) { l1 = acc[e]; i1 = e; }
      int i2 = -1;
      float l2 = -3.4e38f;
#pragma unroll
      for (int e = 0; e < NE; ++e)
        if (e != i1 && acc[e] > l2) { l2 = acc[e]; i2 = e; }
      const float q = expf(l2 - l1);
      const float w1 = 1.f / (1.f + q);
      tok_e[2 * t] = i1;
      tok_e[2 * t + 1] = i2;
      tok_w[2 * t] = w1;
      tok_w[2 * t + 1] = q * w1;
      rank_of[2 * t] = atomicAdd(&cnt[i1], 1);
      rank_of[2 * t + 1] = atomicAdd(&cnt[i2], 1);
    }
  }
  __syncthreads();
  if (tid < NE) blk_cnt[blockIdx.x * NE + tid] = cnt[tid];
}

// ---------------- scatterscan: scan (redundant per block, wave 0) + scatter ----
// r14: merges the old scan+scatter kernels (one fewer launch boundary, no
// cross-block sync needed — 8 KB redundant blk_cnt read per block is free).
// 64 blocks x 256; block b scatters picks [b*256, b*256+256).
__global__ __launch_bounds__(256) void scatterscan_kernel(
    const int* __restrict__ blk_cnt, const int* __restrict__ tok_e,
    const float* __restrict__ tok_w, const int* __restrict__ rank_of,
    int* __restrict__ counts, int* __restrict__ offsets, int* __restrict__ wl_e,
    int* __restrict__ wl_m, int* __restrict__ n_work, int* __restrict__ bucket_tok,
    float* __restrict__ bucket_w, int* __restrict__ pos_of) {
  __shared__ int bb[GB][NE];  // 8 KB: per-gate-block base
  const int tid = threadIdx.x;
  if (tid < 64) {
    const int b = tid;  // lane b handles gate-blocks b*4 .. b*4+3
    int sum[NE], pre[NE], tot[NE];
#pragma unroll
    for (int e = 0; e < NE; ++e) {
      int s = 0;
#pragma unroll
      for (int j = 0; j < 4; ++j) s += blk_cnt[(b * 4 + j) * NE + e];
      sum[e] = s;
    }
#pragma unroll
    for (int e = 0; e < NE; ++e) {
      int v = sum[e];
#pragma unroll
      for (int off = 1; off < 64; off <<= 1) {
        const int u = __shfl_up(v, off);
        if (b >= off) v += u;
      }
      pre[e] = v - sum[e];
      tot[e] = __shfl(v, 63);
    }
    int off_[NE];
    int s = 0;
#pragma unroll
    for (int e = 0; e < NE; ++e) {
      off_[e] = s;
      s += tot[e];
    }
#pragma unroll
    for (int e = 0; e < NE; ++e) {
      int run = off_[e] + pre[e];
#pragma unroll
      for (int j = 0; j < 4; ++j) {
        bb[b * 4 + j][e] = run;
        run += blk_cnt[(b * 4 + j) * NE + e];
      }
    }
    if (blockIdx.x == 0 && b == 0) {
      int idx = 0;
      for (int e = 0; e < NE; ++e) {
        counts[e] = tot[e];
        offsets[e] = off_[e];
        for (int m = 0; m < tot[e] && idx < MAXWL; m += BM) {
          wl_e[idx] = e;
          wl_m[idx] = m;
          ++idx;
        }
      }
      *n_work = idx;
    }
  }
  __syncthreads();
  const int idx = blockIdx.x * 256 + tid;  // pick index
  const int e = tok_e[idx];
  const int g = idx >> 6;                  // 64 picks per gate-block
  const int pos = bb[g][e] + rank_of[idx];
  bucket_tok[pos] = idx >> 1;
  bucket_w[pos] = tok_w[idx];
  pos_of[idx] = pos;
}

// ---------------- transpose+convert: src [E][K][N] f32 -> dst [E][N][K] bf16 ----
__global__ __launch_bounds__(256) void transpose_convert_kernel(const float* __restrict__ src,
                                                                bf16_t* __restrict__ dst, int K,
                                                                int N) {
  __shared__ float tile[64][65];
  const int e = blockIdx.z;
  const int k0 = blockIdx.x * 64;
  const int n0 = blockIdx.y * 64;
  const float* s = src + (size_t)e * K * N;
  bf16_t* d = dst + (size_t)e * K * N;
  const int t = threadIdx.x;
  const int c4 = (t & 15) * 4;
  const int rr = t >> 4;  // 0..15
#pragma unroll
  for (int p = 0; p < 4; ++p) {
    const int r = p * 16 + rr;
    const float4 v = *(const float4*)(s + (size_t)(k0 + r) * N + n0 + c4);
    tile[r][c4] = v.x;
    tile[r][c4 + 1] = v.y;
    tile[r][c4 + 2] = v.z;
    tile[r][c4 + 3] = v.w;
  }
  __syncthreads();
  const int kc = t & 7;
  const int nb = t >> 3;
#pragma unroll
  for (int p = 0; p < 2; ++p) {
    const int n = p * 32 + nb;
    bf16_t o[8];
#pragma unroll
    for (int j = 0; j < 8; ++j) o[j] = (bf16_t)tile[kc * 8 + j][n];
    *(uint4*)(d + (size_t)(n0 + n) * K + k0 + kc * 8) = *(uint4*)o;
  }
}

// ---------------- expert GEMMs: 128x128 tile, 2-buffer, 4 blocks/CU ----------------
// r13 post-mortem: launch_bounds(256,5) = 102-VGPR budget < ~116 live set ->
// acc spilled to scratch (WRITE 68->400 MB, 2.5x slower). r14: budget 128
// (arg=4, 4 blocks/CU); live set trimmed to ~105 by loading af per-mt inside
// the MFMA loop (1 live A-frag instead of 4). 2-buffer single-barrier loop
// (r7/r8-verified). 32 KB LDS x 4 blocks = 128 KB. Per-iter-slot ~4170/4 =
// ~1040 cyc vs r12's 3-buffer 1145 -> TLP over pipeline depth.

__global__ __launch_bounds__(256, 4) void gemm1_kernel(
    const bf16_t* __restrict__ xb, const bf16_t* __restrict__ W1T, const float* __restrict__ b1,
    const int* __restrict__ counts, const int* __restrict__ offsets,
    const int* __restrict__ bucket_tok, const int* __restrict__ wl_e,
    const int* __restrict__ wl_m, const int* __restrict__ n_work, bf16_t* __restrict__ h1) {
  const int widx = blockIdx.x;
  if (widx >= *n_work) return;
  const int e = wl_e[widx];
  const int m_base = wl_m[widx];
  const int n_e = counts[e];
  const int n_base = blockIdx.y * 128;
  const int off = offsets[e];

  __shared__ bf16_t As[2][128 * 32];  // 8 KB each -> 32 KB total
  __shared__ bf16_t Bs[2][128 * 32];

  const int tid = threadIdx.x;
  const int w = tid >> 6;
  const int lane = tid & 63;
  const int quad = lane >> 4;
  const int lrow = lane & 15;
  const int wm = w >> 1;   // 64-row half
  const int wn = w & 1;    // 64-col half

  const int srow = lane >> 2;                        // 16 rows per GLOAD
  const int kch = (((lane & 3) ^ ((lane >> 4) & 3)) * 8);  // pre-swizzled source chunk
  int r0 = m_base + w * 32 + srow;
  int r1 = r0 + 16;
  if (r0 >= n_e) r0 = n_e - 1;
  if (r1 >= n_e) r1 = n_e - 1;
  const bf16_t* ga0 = xb + (size_t)bucket_tok[off + r0] * HD + kch;
  const bf16_t* ga1 = xb + (size_t)bucket_tok[off + r1] * HD + kch;
  const bf16_t* gb0 = W1T + ((size_t)e * ID + n_base + w * 32 + srow) * HD + kch;
  const bf16_t* gb1 = gb0 + (size_t)16 * HD;
  const int laofs0 = w * 1024 + lane * 8;  // rows w*32.. in [128][32]
  const int laofs1 = laofs0 + 512;         // +16 rows

  f32x4 acc[4][4];
#pragma unroll
  for (int mt = 0; mt < 4; ++mt)
#pragma unroll
    for (int nt = 0; nt < 4; ++nt)
#pragma unroll
      for (int r = 0; r < 4; ++r) acc[mt][nt][r] = 0.f;

  // prologue: stage tile 0 into buffer 0
  GLOAD(ga0, &As[0][laofs0]);
  GLOAD(ga1, &As[0][laofs1]);
  GLOAD(gb0, &Bs[0][laofs0]);
  GLOAD(gb1, &Bs[0][laofs1]);
  __syncthreads();

  const int slot = (quad ^ ((lrow >> 2) & 3)) * 8;
#define NT1 (HD / 32)
  for (int kt = 0; kt < NT1; ++kt) {
    const int cur = kt & 1;
    if (kt + 1 < NT1) {  // stage next tile; HBM latency hides under MFMA + TLP
      const int nxt = cur ^ 1;
      const size_t ko = (size_t)(kt + 1) * 32;
      GLOAD(ga0 + ko, &As[nxt][laofs0]);
      GLOAD(ga1 + ko, &As[nxt][laofs1]);
      GLOAD(gb0 + ko, &Bs[nxt][laofs0]);
      GLOAD(gb1 + ko, &Bs[nxt][laofs1]);
    }
    bf16x8 bfr[4];
#pragma unroll
    for (int i = 0; i < 4; ++i)
      bfr[i] = *(const bf16x8*)(&Bs[cur][(wn * 64 + i * 16 + lrow) * 32 + slot]);
#pragma unroll
    for (int mt = 0; mt < 4; ++mt) {
      const bf16x8 af = *(const bf16x8*)(&As[cur][(wm * 64 + mt * 16 + lrow) * 32 + slot]);
#pragma unroll
      for (int nt = 0; nt < 4; ++nt)
        acc[mt][nt] = __builtin_amdgcn_mfma_f32_16x16x32_bf16(bfr[nt], af, acc[mt][nt], 0, 0, 0);
    }
    __syncthreads();  // drains vmcnt(0)+lgkmcnt(0): next tile staged, reads done
  }

  // C^T epilogue: lane owns token gm = ..+lrow; 4 consecutive cols per (nt).
#pragma unroll
  for (int mt = 0; mt < 4; ++mt) {
    const int gm = m_base + wm * 64 + mt * 16 + lrow;
    if (gm < n_e) {
      bf16_t* orow = h1 + (size_t)(off + gm) * ID;
#pragma unroll
      for (int nt = 0; nt < 4; ++nt) {
        const int gi0 = n_base + wn * 64 + nt * 16 + quad * 4;
        const float4 bb = *(const float4*)(b1 + e * ID + gi0);
        const float bv[4] = {bb.x, bb.y, bb.z, bb.w};
        bf16_t o[4];
#pragma unroll
        for (int r = 0; r < 4; ++r) o[r] = (bf16_t)gelu_exact(acc[mt][nt][r] + bv[r]);
        *(uint2*)(orow + gi0) = *(uint2*)o;
      }
    }
  }
}

// gemm2: identical loop; epilogue stores y[pos] = row + b2 (bf16, no atomics).
__global__ __launch_bounds__(256, 4) void gemm2_kernel(
    const bf16_t* __restrict__ h1, const bf16_t* __restrict__ W2T, const float* __restrict__ b2,
    const int* __restrict__ counts, const int* __restrict__ offsets,
    const int* __restrict__ wl_e, const int* __restrict__ wl_m, const int* __restrict__ n_work,
    bf16_t* __restrict__ y) {
  const int widx = blockIdx.x;
  if (widx >= *n_work) return;
  const int e = wl_e[widx];
  const int m_base = wl_m[widx];
  const int n_e = counts[e];
  const int n_base = blockIdx.y * 128;
  const int off = offsets[e];

  __shared__ bf16_t As[2][128 * 32];
  __shared__ bf16_t Bs[2][128 * 32];

  const int tid = threadIdx.x;
  const int w = tid >> 6;
  const int lane = tid & 63;
  const int quad = lane >> 4;
  const int lrow = lane & 15;
  const int wm = w >> 1;
  const int wn = w & 1;

  const int srow = lane >> 2;
  const int kch = (((lane & 3) ^ ((lane >> 4) & 3)) * 8);
  int r0 = m_base + w * 32 + srow;
  int r1 = r0 + 16;
  if (r0 >= n_e) r0 = n_e - 1;
  if (r1 >= n_e) r1 = n_e - 1;
  const bf16_t* ga0 = h1 + (size_t)(off + r0) * ID + kch;
  const bf16_t* ga1 = h1 + (size_t)(off + r1) * ID + kch;
  const bf16_t* gb0 = W2T + ((size_t)e * HD + n_base + w * 32 + srow) * ID + kch;
  const bf16_t* gb1 = gb0 + (size_t)16 * ID;
  const int laofs0 = w * 1024 + lane * 8;
  const int laofs1 = laofs0 + 512;

  f32x4 acc[4][4];
#pragma unroll
  for (int mt = 0; mt < 4; ++mt)
#pragma unroll
    for (int nt = 0; nt < 4; ++nt)
#pragma unroll
      for (int r = 0; r < 4; ++r) acc[mt][nt][r] = 0.f;

  GLOAD(ga0, &As[0][laofs0]);
  GLOAD(ga1, &As[0][laofs1]);
  GLOAD(gb0, &Bs[0][laofs0]);
  GLOAD(gb1, &Bs[0][laofs1]);
  __syncthreads();

  const int slot = (quad ^ ((lrow >> 2) & 3)) * 8;
#define NT2 (ID / 32)
  for (int kt = 0; kt < NT2; ++kt) {
    const int cur = kt & 1;
    if (kt + 1 < NT2) {
      const int nxt = cur ^ 1;
      const size_t ko = (size_t)(kt + 1) * 32;
      GLOAD(ga0 + ko, &As[nxt][laofs0]);
      GLOAD(ga1 + ko, &As[nxt][laofs1]);
      GLOAD(gb0 + ko, &Bs[nxt][laofs0]);
      GLOAD(gb1 + ko, &Bs[nxt][laofs1]);
    }
    bf16x8 bfr[4];
#pragma unroll
    for (int i = 0; i < 4; ++i)
      bfr[i] = *(const bf16x8*)(&Bs[cur][(wn * 64 + i * 16 + lrow) * 32 + slot]);
#pragma unroll
    for (int mt = 0; mt < 4; ++mt) {
      const bf16x8 af = *(const bf16x8*)(&As[cur][(wm * 64 + mt * 16 + lrow) * 32 + slot]);
#pragma unroll
      for (int nt = 0; nt < 4; ++nt)
        acc[mt][nt] = __builtin_amdgcn_mfma_f32_16x16x32_bf16(bfr[nt], af, acc[mt][nt], 0, 0, 0);
    }
    __syncthreads();
  }

#pragma unroll
  for (int mt = 0; mt < 4; ++mt) {
    const int gm = m_base + wm * 64 + mt * 16 + lrow;
    if (gm < n_e) {
      bf16_t* orow = y + (size_t)(off + gm) * HD;
#pragma unroll
      for (int nt = 0; nt < 4; ++nt) {
        const int gi0 = n_base + wn * 64 + nt * 16 + quad * 4;
        const float4 bb = *(const float4*)(b2 + e * HD + gi0);
        const float bv[4] = {bb.x, bb.y, bb.z, bb.w};
        bf16_t o[4];
#pragma unroll
        for (int r = 0; r < 4; ++r) o[r] = (bf16_t)(acc[mt][nt][r] + bv[r]);
        *(uint2*)(orow + gi0) = *(uint2*)o;
      }
    }
  }
}

// ---------------- combine: out[t] = w1*y[p1] + w2*y[p2] ----
__global__ __launch_bounds__(256) void combine_kernel(const bf16_t* __restrict__ y,
                                                      const int* __restrict__ pos_of,
                                                      const float* __restrict__ tok_w,
                                                      float* __restrict__ out) {
  const int gid = blockIdx.x * 256 + threadIdx.x;
  const int t = gid >> 7;             // 128 8-wide chunks per token row
  const int c8 = (gid & 127) * 8;
  const int p1 = pos_of[2 * t];
  const int p2 = pos_of[2 * t + 1];
  const float w1 = tok_w[2 * t];
  const float w2 = tok_w[2 * t + 1];
  const bf16x8 a = *(const bf16x8*)(y + (size_t)p1 * HD + c8);
  const bf16x8 b = *(const bf16x8*)(y + (size_t)p2 * HD + c8);
  float* op = out + (size_t)t * HD + c8;
  float ov[8];
#pragma unroll
  for (int j = 0; j < 8; ++j) ov[j] = w1 * (float)a[j] + w2 * (float)b[j];
  *(float4*)op = make_float4(ov[0], ov[1], ov[2], ov[3]);
  *(float4*)(op + 4) = make_float4(ov[4], ov[5], ov[6], ov[7]);
}

extern "C" void kernel_launch(void* const* d_in, const int* in_sizes, int n_in,
                              void* d_out, int out_size, void* d_ws, size_t ws_size,
                              hipStream_t stream) {
  const float* x = (const float*)d_in[0];
  const float* Wg = (const float*)d_in[1];
  const float* W1 = (const float*)d_in[2];
  const float* b1 = (const float*)d_in[3];
  const float* W2 = (const float*)d_in[4];
  const float* b2 = (const float*)d_in[5];
  float* out = (float*)d_out;
  char* ws = (char*)d_ws;

  int* counts = (int*)(ws + WS_COUNTS);
  int* offsets = (int*)(ws + WS_OFFSETS);
  int* bucket_tok = (int*)(ws + WS_BTOK);
  float* bucket_w = (float*)(ws + WS_BW);
  int* tok_e = (int*)(ws + WS_TE);
  float* tok_w = (float*)(ws + WS_TW);
  int* wl_e = (int*)(ws + WS_WL);
  int* wl_m = wl_e + MAXWL;
  int* n_work = wl_m + MAXWL;
  int* pos_of = (int*)(ws + WS_POS);
  int* rank_of = (int*)(ws + WS_RANK);
  int* blk_cnt = (int*)(ws + WS_BLKC);
  bf16_t* xb = (bf16_t*)(ws + WS_XB);
  bf16_t* h1 = (bf16_t*)(ws + WS_H1);
  bf16_t* WT = (bf16_t*)(ws + WS_WT);
  bf16_t* y = (bf16_t*)(ws + WS_Y);

  gate_kernel<<<GB, 256, 0, stream>>>(x, Wg, xb, tok_e, tok_w, rank_of, blk_cnt);
  scatterscan_kernel<<<TOKS * 2 / 256, 256, 0, stream>>>(blk_cnt, tok_e, tok_w, rank_of, counts,
                                                         offsets, wl_e, wl_m, n_work, bucket_tok,
                                                         bucket_w, pos_of);
  transpose_convert_kernel<<<dim3(HD / 64, ID / 64, NE), 256, 0, stream>>>(W1, WT, HD, ID);
  gemm1_kernel<<<dim3(MAXWL, ID / 128), 256, 0, stream>>>(xb, WT, b1, counts, offsets, bucket_tok,
                                                          wl_e, wl_m, n_work, h1);
  transpose_convert_kernel<<<dim3(ID / 64, HD / 64, NE), 256, 0, stream>>>(W2, WT, ID, HD);
  gemm2_kernel<<<dim3(MAXWL, HD / 128), 256, 0, stream>>>(h1, WT, b2, counts, offsets, wl_e,
                                                          wl_m, n_work, y);
  combine_kernel<<<TOKS * HD / (256 * 8), 256, 0, stream>>>(y, pos_of, tok_w, out);
}

// Round 15
// 449.894 us; speedup vs baseline: 1.8754x; 1.0363x over previous
//
#include <hip/hip_runtime.h>
#include <math.h>

#define TOKS 8192
#define HD 1024
#define ID 2048
#define NE 8

typedef __bf16 bf16_t;
typedef __bf16 bf16x8 __attribute__((ext_vector_type(8)));
typedef float f32x4 __attribute__((ext_vector_type(4)));

// async global->LDS, 16 bytes per lane. LDS dest: wave-uniform base + lane*16.
#define GLOAD(gp, lp)                                                \
  __builtin_amdgcn_global_load_lds(                                  \
      (const __attribute__((address_space(1))) void*)(gp),           \
      (__attribute__((address_space(3))) void*)(lp), 16, 0, 0)

#define WAITV(N) asm volatile("s_waitcnt vmcnt(" #N ")" ::: "memory")
#define WAITL0() asm volatile("s_waitcnt lgkmcnt(0)" ::: "memory")

// branch-free erf-GELU (A&S 7.1.26, |eps|<=1.5e-7 — invisible under bf16 2^-9
// rounding). r11-verified: absmax unchanged vs libm erff.
__device__ __forceinline__ float gelu_exact(float v) {
  const float u = v * 0.70710678118654752f;
  const float a = fabsf(u);
  const float t = 1.f / (1.f + 0.3275911f * a);
  const float poly =
      t * (0.254829592f +
           t * (-0.284496736f +
                t * (1.421413741f + t * (-1.453152027f + t * 1.061405429f))));
  float er = 1.f - poly * __expf(-a * a);
  er = copysignf(er, u);
  return 0.5f * v * (1.f + er);
}

// ---------------- workspace layout (bytes) ----------------
#define WS_COUNTS 0
#define WS_OFFSETS 32
#define WS_BTOK 128
#define WS_BW (128 + 65536)
#define WS_TE (128 + 2 * 65536)
#define WS_TW (128 + 3 * 65536)
#define WS_WL 263168ull
#define WS_POS 274432ull                      // pos_of   [16384] int (64 KB)
#define WS_RANK 339968ull                     // rank_of  [16384] int (64 KB)
#define WS_BLKC 405504ull                     // blk_cnt  [256][8] int (8 KB)
#define WS_XB 524288ull                       // bf16 x  [8192][1024]  = 16.78 MB
#define WS_H1 (WS_XB + 16777216ull)           // bf16 h1 [16384][2048] = 67.1 MB
#define WS_WT (WS_H1 + 67108864ull)           // bf16 WT (W1T then W2T) = 33.55 MB
#define WS_Y (WS_WT + 33554432ull)            // bf16 y  [16384][1024] = 33.55 MB (ends ~151.5 MB)

#define MAXWL 144
#define BM 128      // m-tile (rows of token bucket)
#define GB 256      // gate blocks; 32 tokens each

// ---------------- gating + fused convert + per-block histogram (r14-verified) ----
__global__ __launch_bounds__(256) void gate_kernel(const float* __restrict__ x,
                                                   const float* __restrict__ Wg,
                                                   bf16_t* __restrict__ xb,
                                                   int* __restrict__ tok_e,
                                                   float* __restrict__ tok_w,
                                                   int* __restrict__ rank_of,
                                                   int* __restrict__ blk_cnt) {
  __shared__ float WgT[HD * NE];  // straight copy of Wg (32 KB)
  __shared__ int cnt[NE];
  const int tid = threadIdx.x;
#pragma unroll
  for (int i = 0; i < NE * HD / (256 * 4); ++i) {  // 8 float4 per thread
    const int k = i * 256 + tid;
    ((float4*)WgT)[k] = ((const float4*)Wg)[k];
  }
  if (tid < NE) cnt[tid] = 0;
  __syncthreads();
  const int wv = tid >> 6;
  const int lane = tid & 63;
#pragma unroll
  for (int s = 0; s < 8; ++s) {
    const int t = blockIdx.x * 32 + wv * 8 + s;
    const float* xrow = x + (size_t)t * HD;
    bf16_t* xbrow = xb + (size_t)t * HD;
    float acc[NE];
#pragma unroll
    for (int e = 0; e < NE; ++e) acc[e] = 0.f;
#pragma unroll
    for (int i = 0; i < 16; ++i) {
      const int h = i * 64 + lane;
      const float xv = xrow[h];
      xbrow[h] = (bf16_t)xv;  // fused convert
      const float4 w0 = *(const float4*)(WgT + h * NE);
      const float4 w1 = *(const float4*)(WgT + h * NE + 4);
      acc[0] += xv * w0.x;
      acc[1] += xv * w0.y;
      acc[2] += xv * w0.z;
      acc[3] += xv * w0.w;
      acc[4] += xv * w1.x;
      acc[5] += xv * w1.y;
      acc[6] += xv * w1.z;
      acc[7] += xv * w1.w;
    }
#pragma unroll
    for (int off = 32; off >= 1; off >>= 1) {
#pragma unroll
      for (int e = 0; e < NE; ++e) acc[e] += __shfl_xor(acc[e], off);
    }
    if (lane == 0) {
      int i1 = 0;
      float l1 = acc[0];
#pragma unroll
      for (int e = 1; e < NE; ++e)
        if (acc[e] > l1) { l1 = acc[e]; i1 = e; }
      int i2 = -1;
      float l2 = -3.4e38f;
#pragma unroll
      for (int e = 0; e < NE; ++e)
        if (e != i1 && acc[e] > l2) { l2 = acc[e]; i2 = e; }
      const float q = expf(l2 - l1);
      const float w1 = 1.f / (1.f + q);
      tok_e[2 * t] = i1;
      tok_e[2 * t + 1] = i2;
      tok_w[2 * t] = w1;
      tok_w[2 * t + 1] = q * w1;
      rank_of[2 * t] = atomicAdd(&cnt[i1], 1);
      rank_of[2 * t + 1] = atomicAdd(&cnt[i2], 1);
    }
  }
  __syncthreads();
  if (tid < NE) blk_cnt[blockIdx.x * NE + tid] = cnt[tid];
}

// ---------------- scatterscan: scan (redundant per block, wave 0) + scatter ----
// (r14-verified) 64 blocks x 256; block b scatters picks [b*256, b*256+256).
__global__ __launch_bounds__(256) void scatterscan_kernel(
    const int* __restrict__ blk_cnt, const int* __restrict__ tok_e,
    const float* __restrict__ tok_w, const int* __restrict__ rank_of,
    int* __restrict__ counts, int* __restrict__ offsets, int* __restrict__ wl_e,
    int* __restrict__ wl_m, int* __restrict__ n_work, int* __restrict__ bucket_tok,
    float* __restrict__ bucket_w, int* __restrict__ pos_of) {
  __shared__ int bb[GB][NE];  // 8 KB: per-gate-block base
  const int tid = threadIdx.x;
  if (tid < 64) {
    const int b = tid;  // lane b handles gate-blocks b*4 .. b*4+3
    int sum[NE], pre[NE], tot[NE];
#pragma unroll
    for (int e = 0; e < NE; ++e) {
      int s = 0;
#pragma unroll
      for (int j = 0; j < 4; ++j) s += blk_cnt[(b * 4 + j) * NE + e];
      sum[e] = s;
    }
#pragma unroll
    for (int e = 0; e < NE; ++e) {
      int v = sum[e];
#pragma unroll
      for (int off = 1; off < 64; off <<= 1) {
        const int u = __shfl_up(v, off);
        if (b >= off) v += u;
      }
      pre[e] = v - sum[e];
      tot[e] = __shfl(v, 63);
    }
    int off_[NE];
    int s = 0;
#pragma unroll
    for (int e = 0; e < NE; ++e) {
      off_[e] = s;
      s += tot[e];
    }
#pragma unroll
    for (int e = 0; e < NE; ++e) {
      int run = off_[e] + pre[e];
#pragma unroll
      for (int j = 0; j < 4; ++j) {
        bb[b * 4 + j][e] = run;
        run += blk_cnt[(b * 4 + j) * NE + e];
      }
    }
    if (blockIdx.x == 0 && b == 0) {
      int idx = 0;
      for (int e = 0; e < NE; ++e) {
        counts[e] = tot[e];
        offsets[e] = off_[e];
        for (int m = 0; m < tot[e] && idx < MAXWL; m += BM) {
          wl_e[idx] = e;
          wl_m[idx] = m;
          ++idx;
        }
      }
      *n_work = idx;
    }
  }
  __syncthreads();
  const int idx = blockIdx.x * 256 + tid;  // pick index
  const int e = tok_e[idx];
  const int g = idx >> 6;                  // 64 picks per gate-block
  const int pos = bb[g][e] + rank_of[idx];
  bucket_tok[pos] = idx >> 1;
  bucket_w[pos] = tok_w[idx];
  pos_of[idx] = pos;
}

// ---------------- transpose+convert: src [E][K][N] f32 -> dst [E][N][K] bf16 ----
__global__ __launch_bounds__(256) void transpose_convert_kernel(const float* __restrict__ src,
                                                                bf16_t* __restrict__ dst, int K,
                                                                int N) {
  __shared__ float tile[64][65];
  const int e = blockIdx.z;
  const int k0 = blockIdx.x * 64;
  const int n0 = blockIdx.y * 64;
  const float* s = src + (size_t)e * K * N;
  bf16_t* d = dst + (size_t)e * K * N;
  const int t = threadIdx.x;
  const int c4 = (t & 15) * 4;
  const int rr = t >> 4;  // 0..15
#pragma unroll
  for (int p = 0; p < 4; ++p) {
    const int r = p * 16 + rr;
    const float4 v = *(const float4*)(s + (size_t)(k0 + r) * N + n0 + c4);
    tile[r][c4] = v.x;
    tile[r][c4 + 1] = v.y;
    tile[r][c4 + 2] = v.z;
    tile[r][c4 + 3] = v.w;
  }
  __syncthreads();
  const int kc = t & 7;
  const int nb = t >> 3;
#pragma unroll
  for (int p = 0; p < 2; ++p) {
    const int n = p * 32 + nb;
    bf16_t o[8];
#pragma unroll
    for (int j = 0; j < 8; ++j) o[j] = (bf16_t)tile[kc * 8 + j][n];
    *(uint4*)(d + (size_t)(n0 + n) * K + k0 + kc * 8) = *(uint4*)o;
  }
}

// ---------------- expert GEMMs: 128x128 tile, 3-buffer counted-vmcnt ----------------
// r12-verified BEST (gemm1 128 us, total 447). r13 (5 blk/CU): VGPR-budget 102
// < live set -> acc spill, 2.5x slower. r14 (2-buf, 4 blk/CU): occupancy
// 28->33% but per-iter drain cost + L2 thrash (FETCH +25%) made it SLOWER
// (137 us). Occupancy is a hill; 3 blocks/CU x 3-buffer is its top.

__global__ __launch_bounds__(256, 3) void gemm1_kernel(
    const bf16_t* __restrict__ xb, const bf16_t* __restrict__ W1T, const float* __restrict__ b1,
    const int* __restrict__ counts, const int* __restrict__ offsets,
    const int* __restrict__ bucket_tok, const int* __restrict__ wl_e,
    const int* __restrict__ wl_m, const int* __restrict__ n_work, bf16_t* __restrict__ h1) {
  const int widx = blockIdx.x;
  if (widx >= *n_work) return;
  const int e = wl_e[widx];
  const int m_base = wl_m[widx];
  const int n_e = counts[e];
  const int n_base = blockIdx.y * 128;
  const int off = offsets[e];

  __shared__ bf16_t As[3][128 * 32];  // 8 KB each
  __shared__ bf16_t Bs[3][128 * 32];

  const int tid = threadIdx.x;
  const int w = tid >> 6;
  const int lane = tid & 63;
  const int quad = lane >> 4;
  const int lrow = lane & 15;
  const int wm = w >> 1;   // 64-row half
  const int wn = w & 1;    // 64-col half

  const int srow = lane >> 2;                        // 16 rows per GLOAD
  const int kch = (((lane & 3) ^ ((lane >> 4) & 3)) * 8);  // pre-swizzled source chunk
  int r0 = m_base + w * 32 + srow;
  int r1 = r0 + 16;
  if (r0 >= n_e) r0 = n_e - 1;
  if (r1 >= n_e) r1 = n_e - 1;
  const bf16_t* ga0 = xb + (size_t)bucket_tok[off + r0] * HD + kch;
  const bf16_t* ga1 = xb + (size_t)bucket_tok[off + r1] * HD + kch;
  const bf16_t* gb0 = W1T + ((size_t)e * ID + n_base + w * 32 + srow) * HD + kch;
  const bf16_t* gb1 = gb0 + (size_t)16 * HD;
  const int laofs0 = w * 1024 + lane * 8;  // rows w*32.. in [128][32]
  const int laofs1 = laofs0 + 512;         // +16 rows

  f32x4 acc[4][4];
#pragma unroll
  for (int mt = 0; mt < 4; ++mt)
#pragma unroll
    for (int nt = 0; nt < 4; ++nt)
#pragma unroll
      for (int r = 0; r < 4; ++r) acc[mt][nt][r] = 0.f;

  // prologue: stage tiles 0 and 1 (8 outstanding GLOADs/wave)
#pragma unroll
  for (int p = 0; p < 2; ++p) {
    const size_t ko = (size_t)p * 32;
    GLOAD(ga0 + ko, &As[p][laofs0]);
    GLOAD(ga1 + ko, &As[p][laofs1]);
    GLOAD(gb0 + ko, &Bs[p][laofs0]);
    GLOAD(gb1 + ko, &Bs[p][laofs1]);
  }

  const int slot = (quad ^ ((lrow >> 2) & 3)) * 8;
  int cur = 0;        // kt % 3, carried (no div in loop)
  int pre = 2;        // (kt+2) % 3, carried
#define NT1 (HD / 32)
  for (int kt = 0; kt < NT1; ++kt) {
    WAITL0();                          // prior iter's ds_reads done (per-wave)
    __builtin_amdgcn_s_barrier();      // #1: buf[(kt+2)%3] free to overwrite
    if (kt + 2 < NT1) {
      const size_t ko = (size_t)(kt + 2) * 32;
      GLOAD(ga0 + ko, &As[pre][laofs0]);
      GLOAD(ga1 + ko, &As[pre][laofs1]);
      GLOAD(gb0 + ko, &Bs[pre][laofs0]);
      GLOAD(gb1 + ko, &Bs[pre][laofs1]);
      WAITV(8);                        // tile kt landed; kt+1,kt+2 in flight
    } else if (kt + 1 < NT1) {
      WAITV(4);
    } else {
      WAITV(0);
    }
    __builtin_amdgcn_s_barrier();      // #2: tile kt visible to all waves
    __builtin_amdgcn_sched_barrier(0); // fence: no ds_read hoists above
    bf16x8 af[4], bfr[4];
#pragma unroll
    for (int i = 0; i < 4; ++i) {
      af[i] = *(const bf16x8*)(&As[cur][(wm * 64 + i * 16 + lrow) * 32 + slot]);
      bfr[i] = *(const bf16x8*)(&Bs[cur][(wn * 64 + i * 16 + lrow) * 32 + slot]);
    }
    __builtin_amdgcn_s_setprio(1);
#pragma unroll
    for (int mt = 0; mt < 4; ++mt)
#pragma unroll
      for (int nt = 0; nt < 4; ++nt)
        acc[mt][nt] =
            __builtin_amdgcn_mfma_f32_16x16x32_bf16(bfr[nt], af[mt], acc[mt][nt], 0, 0, 0);
    __builtin_amdgcn_s_setprio(0);
    cur = (cur == 2) ? 0 : cur + 1;
    pre = (pre == 2) ? 0 : pre + 1;
  }

  // C^T epilogue: lane owns token gm = ..+lrow; 4 consecutive cols per (nt).
#pragma unroll
  for (int mt = 0; mt < 4; ++mt) {
    const int gm = m_base + wm * 64 + mt * 16 + lrow;
    if (gm < n_e) {
      bf16_t* orow = h1 + (size_t)(off + gm) * ID;
#pragma unroll
      for (int nt = 0; nt < 4; ++nt) {
        const int gi0 = n_base + wn * 64 + nt * 16 + quad * 4;
        const float4 bb = *(const float4*)(b1 + e * ID + gi0);
        const float bv[4] = {bb.x, bb.y, bb.z, bb.w};
        bf16_t o[4];
#pragma unroll
        for (int r = 0; r < 4; ++r) o[r] = (bf16_t)gelu_exact(acc[mt][nt][r] + bv[r]);
        *(uint2*)(orow + gi0) = *(uint2*)o;
      }
    }
  }
}

// gemm2: identical loop; epilogue stores y[pos] = row + b2 (bf16, no atomics).
__global__ __launch_bounds__(256, 3) void gemm2_kernel(
    const bf16_t* __restrict__ h1, const bf16_t* __restrict__ W2T, const float* __restrict__ b2,
    const int* __restrict__ counts, const int* __restrict__ offsets,
    const int* __restrict__ wl_e, const int* __restrict__ wl_m, const int* __restrict__ n_work,
    bf16_t* __restrict__ y) {
  const int widx = blockIdx.x;
  if (widx >= *n_work) return;
  const int e = wl_e[widx];
  const int m_base = wl_m[widx];
  const int n_e = counts[e];
  const int n_base = blockIdx.y * 128;
  const int off = offsets[e];

  __shared__ bf16_t As[3][128 * 32];
  __shared__ bf16_t Bs[3][128 * 32];

  const int tid = threadIdx.x;
  const int w = tid >> 6;
  const int lane = tid & 63;
  const int quad = lane >> 4;
  const int lrow = lane & 15;
  const int wm = w >> 1;
  const int wn = w & 1;

  const int srow = lane >> 2;
  const int kch = (((lane & 3) ^ ((lane >> 4) & 3)) * 8);
  int r0 = m_base + w * 32 + srow;
  int r1 = r0 + 16;
  if (r0 >= n_e) r0 = n_e - 1;
  if (r1 >= n_e) r1 = n_e - 1;
  const bf16_t* ga0 = h1 + (size_t)(off + r0) * ID + kch;
  const bf16_t* ga1 = h1 + (size_t)(off + r1) * ID + kch;
  const bf16_t* gb0 = W2T + ((size_t)e * HD + n_base + w * 32 + srow) * ID + kch;
  const bf16_t* gb1 = gb0 + (size_t)16 * ID;
  const int laofs0 = w * 1024 + lane * 8;
  const int laofs1 = laofs0 + 512;

  f32x4 acc[4][4];
#pragma unroll
  for (int mt = 0; mt < 4; ++mt)
#pragma unroll
    for (int nt = 0; nt < 4; ++nt)
#pragma unroll
      for (int r = 0; r < 4; ++r) acc[mt][nt][r] = 0.f;

#pragma unroll
  for (int p = 0; p < 2; ++p) {
    const size_t ko = (size_t)p * 32;
    GLOAD(ga0 + ko, &As[p][laofs0]);
    GLOAD(ga1 + ko, &As[p][laofs1]);
    GLOAD(gb0 + ko, &Bs[p][laofs0]);
    GLOAD(gb1 + ko, &Bs[p][laofs1]);
  }

  const int slot = (quad ^ ((lrow >> 2) & 3)) * 8;
  int cur = 0;
  int pre = 2;
#define NT2 (ID / 32)
  for (int kt = 0; kt < NT2; ++kt) {
    WAITL0();
    __builtin_amdgcn_s_barrier();
    if (kt + 2 < NT2) {
      const size_t ko = (size_t)(kt + 2) * 32;
      GLOAD(ga0 + ko, &As[pre][laofs0]);
      GLOAD(ga1 + ko, &As[pre][laofs1]);
      GLOAD(gb0 + ko, &Bs[pre][laofs0]);
      GLOAD(gb1 + ko, &Bs[pre][laofs1]);
      WAITV(8);
    } else if (kt + 1 < NT2) {
      WAITV(4);
    } else {
      WAITV(0);
    }
    __builtin_amdgcn_s_barrier();
    __builtin_amdgcn_sched_barrier(0);
    bf16x8 af[4], bfr[4];
#pragma unroll
    for (int i = 0; i < 4; ++i) {
      af[i] = *(const bf16x8*)(&As[cur][(wm * 64 + i * 16 + lrow) * 32 + slot]);
      bfr[i] = *(const bf16x8*)(&Bs[cur][(wn * 64 + i * 16 + lrow) * 32 + slot]);
    }
    __builtin_amdgcn_s_setprio(1);
#pragma unroll
    for (int mt = 0; mt < 4; ++mt)
#pragma unroll
      for (int nt = 0; nt < 4; ++nt)
        acc[mt][nt] =
            __builtin_amdgcn_mfma_f32_16x16x32_bf16(bfr[nt], af[mt], acc[mt][nt], 0, 0, 0);
    __builtin_amdgcn_s_setprio(0);
    cur = (cur == 2) ? 0 : cur + 1;
    pre = (pre == 2) ? 0 : pre + 1;
  }

#pragma unroll
  for (int mt = 0; mt < 4; ++mt) {
    const int gm = m_base + wm * 64 + mt * 16 + lrow;
    if (gm < n_e) {
      bf16_t* orow = y + (size_t)(off + gm) * HD;
#pragma unroll
      for (int nt = 0; nt < 4; ++nt) {
        const int gi0 = n_base + wn * 64 + nt * 16 + quad * 4;
        const float4 bb = *(const float4*)(b2 + e * HD + gi0);
        const float bv[4] = {bb.x, bb.y, bb.z, bb.w};
        bf16_t o[4];
#pragma unroll
        for (int r = 0; r < 4; ++r) o[r] = (bf16_t)(acc[mt][nt][r] + bv[r]);
        *(uint2*)(orow + gi0) = *(uint2*)o;
      }
    }
  }
}

// ---------------- combine: out[t] = w1*y[p1] + w2*y[p2] ----
__global__ __launch_bounds__(256) void combine_kernel(const bf16_t* __restrict__ y,
                                                      const int* __restrict__ pos_of,
                                                      const float* __restrict__ tok_w,
                                                      float* __restrict__ out) {
  const int gid = blockIdx.x * 256 + threadIdx.x;
  const int t = gid >> 7;             // 128 8-wide chunks per token row
  const int c8 = (gid & 127) * 8;
  const int p1 = pos_of[2 * t];
  const int p2 = pos_of[2 * t + 1];
  const float w1 = tok_w[2 * t];
  const float w2 = tok_w[2 * t + 1];
  const bf16x8 a = *(const bf16x8*)(y + (size_t)p1 * HD + c8);
  const bf16x8 b = *(const bf16x8*)(y + (size_t)p2 * HD + c8);
  float* op = out + (size_t)t * HD + c8;
  float ov[8];
#pragma unroll
  for (int j = 0; j < 8; ++j) ov[j] = w1 * (float)a[j] + w2 * (float)b[j];
  *(float4*)op = make_float4(ov[0], ov[1], ov[2], ov[3]);
  *(float4*)(op + 4) = make_float4(ov[4], ov[5], ov[6], ov[7]);
}

extern "C" void kernel_launch(void* const* d_in, const int* in_sizes, int n_in,
                              void* d_out, int out_size, void* d_ws, size_t ws_size,
                              hipStream_t stream) {
  const float* x = (const float*)d_in[0];
  const float* Wg = (const float*)d_in[1];
  const float* W1 = (const float*)d_in[2];
  const float* b1 = (const float*)d_in[3];
  const float* W2 = (const float*)d_in[4];
  const float* b2 = (const float*)d_in[5];
  float* out = (float*)d_out;
  char* ws = (char*)d_ws;

  int* counts = (int*)(ws + WS_COUNTS);
  int* offsets = (int*)(ws + WS_OFFSETS);
  int* bucket_tok = (int*)(ws + WS_BTOK);
  float* bucket_w = (float*)(ws + WS_BW);
  int* tok_e = (int*)(ws + WS_TE);
  float* tok_w = (float*)(ws + WS_TW);
  int* wl_e = (int*)(ws + WS_WL);
  int* wl_m = wl_e + MAXWL;
  int* n_work = wl_m + MAXWL;
  int* pos_of = (int*)(ws + WS_POS);
  int* rank_of = (int*)(ws + WS_RANK);
  int* blk_cnt = (int*)(ws + WS_BLKC);
  bf16_t* xb = (bf16_t*)(ws + WS_XB);
  bf16_t* h1 = (bf16_t*)(ws + WS_H1);
  bf16_t* WT = (bf16_t*)(ws + WS_WT);
  bf16_t* y = (bf16_t*)(ws + WS_Y);

  gate_kernel<<<GB, 256, 0, stream>>>(x, Wg, xb, tok_e, tok_w, rank_of, blk_cnt);
  scatterscan_kernel<<<TOKS * 2 / 256, 256, 0, stream>>>(blk_cnt, tok_e, tok_w, rank_of, counts,
                                                         offsets, wl_e, wl_m, n_work, bucket_tok,
                                                         bucket_w, pos_of);
  transpose_convert_kernel<<<dim3(HD / 64, ID / 64, NE), 256, 0, stream>>>(W1, WT, HD, ID);
  gemm1_kernel<<<dim3(MAXWL, ID / 128), 256, 0, stream>>>(xb, WT, b1, counts, offsets, bucket_tok,
                                                          wl_e, wl_m, n_work, h1);
  transpose_convert_kernel<<<dim3(ID / 64, HD / 64, NE), 256, 0, stream>>>(W2, WT, ID, HD);
  gemm2_kernel<<<dim3(MAXWL, HD / 128), 256, 0, stream>>>(h1, WT, b2, counts, offsets, wl_e,
                                                          wl_m, n_work, y);
  combine_kernel<<<TOKS * HD / (256 * 8), 256, 0, stream>>>(y, pos_of, tok_w, out);
}

// Round 16
// 440.201 us; speedup vs baseline: 1.9167x; 1.0220x over previous
//
#include <hip/hip_runtime.h>
#include <math.h>

#define TOKS 8192
#define HD 1024
#define ID 2048
#define NE 8

typedef __bf16 bf16_t;
typedef __bf16 bf16x8 __attribute__((ext_vector_type(8)));
typedef float f32x4 __attribute__((ext_vector_type(4)));

// async global->LDS, 16 bytes per lane. LDS dest: wave-uniform base + lane*16.
#define GLOAD(gp, lp)                                                \
  __builtin_amdgcn_global_load_lds(                                  \
      (const __attribute__((address_space(1))) void*)(gp),           \
      (__attribute__((address_space(3))) void*)(lp), 16, 0, 0)

#define WAITV(N) asm volatile("s_waitcnt vmcnt(" #N ")" ::: "memory")
#define WAITL0() asm volatile("s_waitcnt lgkmcnt(0)" ::: "memory")

// branch-free erf-GELU (A&S 7.1.26, |eps|<=1.5e-7 — invisible under bf16 2^-9
// rounding). r11-verified: absmax unchanged vs libm erff.
__device__ __forceinline__ float gelu_exact(float v) {
  const float u = v * 0.70710678118654752f;
  const float a = fabsf(u);
  const float t = 1.f / (1.f + 0.3275911f * a);
  const float poly =
      t * (0.254829592f +
           t * (-0.284496736f +
                t * (1.421413741f + t * (-1.453152027f + t * 1.061405429f))));
  float er = 1.f - poly * __expf(-a * a);
  er = copysignf(er, u);
  return 0.5f * v * (1.f + er);
}

// ---------------- workspace layout (bytes) ----------------
#define WS_COUNTS 0
#define WS_OFFSETS 32
#define WS_BTOK 128
#define WS_BW (128 + 65536)
#define WS_TE (128 + 2 * 65536)
#define WS_TW (128 + 3 * 65536)
#define WS_WL 263168ull
#define WS_POS 274432ull                      // pos_of   [16384] int (64 KB)
#define WS_RANK 339968ull                     // rank_of  [16384] int (64 KB)
#define WS_BLKC 405504ull                     // blk_cnt  [256][8] int (8 KB)
#define WS_XB 524288ull                       // bf16 x  [8192][1024]  = 16.78 MB
#define WS_H1 (WS_XB + 16777216ull)           // bf16 h1 [16384][2048] = 67.1 MB
#define WS_WT (WS_H1 + 67108864ull)           // bf16 W2T = 33.55 MB
#define WS_Y (WS_WT + 33554432ull)            // bf16: W1T until gemm1 done, then y
                                              //       [16384][1024] = 33.55 MB (end ~151.5 MB)
// Lifetime aliasing (r16): both transposes now run up-front (fused prep), so
// W1T and W2T need distinct buffers. W1T lives in the y region: y is first
// written by gemm2, by which time W1T (read only by gemm1) is dead. No new
// workspace beyond the r8-verified 151.5 MB.

#define MAXWL 144
#define BM 128      // m-tile (rows of token bucket)
#define GB 256      // gate blocks; 32 tokens each
#define TBLK 4096   // transpose blocks per weight tensor: (K/64)*(N/64)*NE = 512*8

// ---------------- prep: fused gate + W1-transpose + W2-transpose ----------------
// r16: gate(x,Wg) and the two weight transposes are independent; serialized
// launches left CUs idle (~200 us of non-GEMM time vs ~95 ideal). One kernel,
// block-range dispatch: [0,GB) gate, [GB,GB+TBLK) W1->W1T, rest W2->W2T.
// 32 KB LDS union (gate Wg copy / transpose 64x65 f32 tile); all barriers
// block-uniform. Gate blocks placed first (longest, latency-bound).
__global__ __launch_bounds__(256) void prep_kernel(
    const float* __restrict__ x, const float* __restrict__ Wg, const float* __restrict__ W1,
    const float* __restrict__ W2, bf16_t* __restrict__ xb, bf16_t* __restrict__ w1t,
    bf16_t* __restrict__ w2t, int* __restrict__ tok_e, float* __restrict__ tok_w,
    int* __restrict__ rank_of, int* __restrict__ blk_cnt) {
  __shared__ __align__(16) float smem[HD * NE];  // 32 KB union
  __shared__ int cnt[NE];
  const int bid = blockIdx.x;
  const int tid = threadIdx.x;

  if (bid < GB) {
    // ---- gate path (r14-verified logic) ----
#pragma unroll
    for (int i = 0; i < NE * HD / (256 * 4); ++i) {  // 8 float4 per thread
      const int k = i * 256 + tid;
      ((float4*)smem)[k] = ((const float4*)Wg)[k];
    }
    if (tid < NE) cnt[tid] = 0;
    __syncthreads();
    const int wv = tid >> 6;
    const int lane = tid & 63;
#pragma unroll
    for (int s = 0; s < 8; ++s) {
      const int t = bid * 32 + wv * 8 + s;
      const float* xrow = x + (size_t)t * HD;
      bf16_t* xbrow = xb + (size_t)t * HD;
      float acc[NE];
#pragma unroll
      for (int e = 0; e < NE; ++e) acc[e] = 0.f;
#pragma unroll
      for (int i = 0; i < 16; ++i) {
        const int h = i * 64 + lane;
        const float xv = xrow[h];
        xbrow[h] = (bf16_t)xv;  // fused convert
        const float4 w0 = *(const float4*)(smem + h * NE);
        const float4 w1 = *(const float4*)(smem + h * NE + 4);
        acc[0] += xv * w0.x;
        acc[1] += xv * w0.y;
        acc[2] += xv * w0.z;
        acc[3] += xv * w0.w;
        acc[4] += xv * w1.x;
        acc[5] += xv * w1.y;
        acc[6] += xv * w1.z;
        acc[7] += xv * w1.w;
      }
#pragma unroll
      for (int off = 32; off >= 1; off >>= 1) {
#pragma unroll
        for (int e = 0; e < NE; ++e) acc[e] += __shfl_xor(acc[e], off);
      }
      if (lane == 0) {
        int i1 = 0;
        float l1 = acc[0];
#pragma unroll
        for (int e = 1; e < NE; ++e)
          if (acc[e] > l1) { l1 = acc[e]; i1 = e; }
        int i2 = -1;
        float l2 = -3.4e38f;
#pragma unroll
        for (int e = 0; e < NE; ++e)
          if (e != i1 && acc[e] > l2) { l2 = acc[e]; i2 = e; }
        const float q = expf(l2 - l1);
        const float w1 = 1.f / (1.f + q);
        tok_e[2 * t] = i1;
        tok_e[2 * t + 1] = i2;
        tok_w[2 * t] = w1;
        tok_w[2 * t + 1] = q * w1;
        rank_of[2 * t] = atomicAdd(&cnt[i1], 1);
        rank_of[2 * t + 1] = atomicAdd(&cnt[i2], 1);
      }
    }
    __syncthreads();
    if (tid < NE) blk_cnt[bid * NE + tid] = cnt[tid];
  } else {
    // ---- transpose path (r11-verified body): src [E][K][N] f32 -> dst [E][N][K] bf16
    float(*tile)[65] = (float(*)[65])smem;  // 16.6 KB of the union
    const float* src;
    bf16_t* dst;
    int K, N, t;
    if (bid < GB + TBLK) {
      t = bid - GB;
      K = HD;
      N = ID;
      src = W1;
      dst = w1t;
    } else {
      t = bid - GB - TBLK;
      K = ID;
      N = HD;
      src = W2;
      dst = w2t;
    }
    const int ktiles = K / 64;
    const int ntiles = N / 64;
    const int kx = t % ktiles;
    const int ny = (t / ktiles) % ntiles;
    const int e = t / (ktiles * ntiles);
    const int k0 = kx * 64;
    const int n0 = ny * 64;
    const float* s = src + (size_t)e * K * N;
    bf16_t* d = dst + (size_t)e * K * N;
    const int c4 = (tid & 15) * 4;
    const int rr = tid >> 4;  // 0..15
#pragma unroll
    for (int p = 0; p < 4; ++p) {
      const int r = p * 16 + rr;
      const float4 v = *(const float4*)(s + (size_t)(k0 + r) * N + n0 + c4);
      tile[r][c4] = v.x;
      tile[r][c4 + 1] = v.y;
      tile[r][c4 + 2] = v.z;
      tile[r][c4 + 3] = v.w;
    }
    __syncthreads();
    const int kc = tid & 7;
    const int nb = tid >> 3;
#pragma unroll
    for (int p = 0; p < 2; ++p) {
      const int n = p * 32 + nb;
      bf16_t o[8];
#pragma unroll
      for (int j = 0; j < 8; ++j) o[j] = (bf16_t)tile[kc * 8 + j][n];
      *(uint4*)(d + (size_t)(n0 + n) * K + k0 + kc * 8) = *(uint4*)o;
    }
  }
}

// ---------------- scatterscan: scan (redundant per block, wave 0) + scatter ----
// (r14-verified) 64 blocks x 256; block b scatters picks [b*256, b*256+256).
__global__ __launch_bounds__(256) void scatterscan_kernel(
    const int* __restrict__ blk_cnt, const int* __restrict__ tok_e,
    const float* __restrict__ tok_w, const int* __restrict__ rank_of,
    int* __restrict__ counts, int* __restrict__ offsets, int* __restrict__ wl_e,
    int* __restrict__ wl_m, int* __restrict__ n_work, int* __restrict__ bucket_tok,
    float* __restrict__ bucket_w, int* __restrict__ pos_of) {
  __shared__ int bb[GB][NE];  // 8 KB: per-gate-block base
  const int tid = threadIdx.x;
  if (tid < 64) {
    const int b = tid;  // lane b handles gate-blocks b*4 .. b*4+3
    int sum[NE], pre[NE], tot[NE];
#pragma unroll
    for (int e = 0; e < NE; ++e) {
      int s = 0;
#pragma unroll
      for (int j = 0; j < 4; ++j) s += blk_cnt[(b * 4 + j) * NE + e];
      sum[e] = s;
    }
#pragma unroll
    for (int e = 0; e < NE; ++e) {
      int v = sum[e];
#pragma unroll
      for (int off = 1; off < 64; off <<= 1) {
        const int u = __shfl_up(v, off);
        if (b >= off) v += u;
      }
      pre[e] = v - sum[e];
      tot[e] = __shfl(v, 63);
    }
    int off_[NE];
    int s = 0;
#pragma unroll
    for (int e = 0; e < NE; ++e) {
      off_[e] = s;
      s += tot[e];
    }
#pragma unroll
    for (int e = 0; e < NE; ++e) {
      int run = off_[e] + pre[e];
#pragma unroll
      for (int j = 0; j < 4; ++j) {
        bb[b * 4 + j][e] = run;
        run += blk_cnt[(b * 4 + j) * NE + e];
      }
    }
    if (blockIdx.x == 0 && b == 0) {
      int idx = 0;
      for (int e = 0; e < NE; ++e) {
        counts[e] = tot[e];
        offsets[e] = off_[e];
        for (int m = 0; m < tot[e] && idx < MAXWL; m += BM) {
          wl_e[idx] = e;
          wl_m[idx] = m;
          ++idx;
        }
      }
      *n_work = idx;
    }
  }
  __syncthreads();
  const int idx = blockIdx.x * 256 + tid;  // pick index
  const int e = tok_e[idx];
  const int g = idx >> 6;                  // 64 picks per gate-block
  const int pos = bb[g][e] + rank_of[idx];
  bucket_tok[pos] = idx >> 1;
  bucket_w[pos] = tok_w[idx];
  pos_of[idx] = pos;
}

// ---------------- expert GEMMs: 128x128 tile, 3-buffer counted-vmcnt ----------------
// r12/r15-verified BEST (gemm1 127 us). r13 (5 blk/CU): VGPR spill, 2.5x
// slower. r14 (2-buf, 4 blk/CU): occupancy up but drain cost + L2 thrash made
// it slower. Occupancy is a hill; 3 blocks/CU x 3-buffer is its top.

__global__ __launch_bounds__(256, 3) void gemm1_kernel(
    const bf16_t* __restrict__ xb, const bf16_t* __restrict__ W1T, const float* __restrict__ b1,
    const int* __restrict__ counts, const int* __restrict__ offsets,
    const int* __restrict__ bucket_tok, const int* __restrict__ wl_e,
    const int* __restrict__ wl_m, const int* __restrict__ n_work, bf16_t* __restrict__ h1) {
  const int widx = blockIdx.x;
  if (widx >= *n_work) return;
  const int e = wl_e[widx];
  const int m_base = wl_m[widx];
  const int n_e = counts[e];
  const int n_base = blockIdx.y * 128;
  const int off = offsets[e];

  __shared__ bf16_t As[3][128 * 32];  // 8 KB each
  __shared__ bf16_t Bs[3][128 * 32];

  const int tid = threadIdx.x;
  const int w = tid >> 6;
  const int lane = tid & 63;
  const int quad = lane >> 4;
  const int lrow = lane & 15;
  const int wm = w >> 1;   // 64-row half
  const int wn = w & 1;    // 64-col half

  const int srow = lane >> 2;                        // 16 rows per GLOAD
  const int kch = (((lane & 3) ^ ((lane >> 4) & 3)) * 8);  // pre-swizzled source chunk
  int r0 = m_base + w * 32 + srow;
  int r1 = r0 + 16;
  if (r0 >= n_e) r0 = n_e - 1;
  if (r1 >= n_e) r1 = n_e - 1;
  const bf16_t* ga0 = xb + (size_t)bucket_tok[off + r0] * HD + kch;
  const bf16_t* ga1 = xb + (size_t)bucket_tok[off + r1] * HD + kch;
  const bf16_t* gb0 = W1T + ((size_t)e * ID + n_base + w * 32 + srow) * HD + kch;
  const bf16_t* gb1 = gb0 + (size_t)16 * HD;
  const int laofs0 = w * 1024 + lane * 8;  // rows w*32.. in [128][32]
  const int laofs1 = laofs0 + 512;         // +16 rows

  f32x4 acc[4][4];
#pragma unroll
  for (int mt = 0; mt < 4; ++mt)
#pragma unroll
    for (int nt = 0; nt < 4; ++nt)
#pragma unroll
      for (int r = 0; r < 4; ++r) acc[mt][nt][r] = 0.f;

  // prologue: stage tiles 0 and 1 (8 outstanding GLOADs/wave)
#pragma unroll
  for (int p = 0; p < 2; ++p) {
    const size_t ko = (size_t)p * 32;
    GLOAD(ga0 + ko, &As[p][laofs0]);
    GLOAD(ga1 + ko, &As[p][laofs1]);
    GLOAD(gb0 + ko, &Bs[p][laofs0]);
    GLOAD(gb1 + ko, &Bs[p][laofs1]);
  }

  const int slot = (quad ^ ((lrow >> 2) & 3)) * 8;
  int cur = 0;        // kt % 3, carried (no div in loop)
  int pre = 2;        // (kt+2) % 3, carried
#define NT1 (HD / 32)
  for (int kt = 0; kt < NT1; ++kt) {
    WAITL0();                          // prior iter's ds_reads done (per-wave)
    __builtin_amdgcn_s_barrier();      // #1: buf[(kt+2)%3] free to overwrite
    if (kt + 2 < NT1) {
      const size_t ko = (size_t)(kt + 2) * 32;
      GLOAD(ga0 + ko, &As[pre][laofs0]);
      GLOAD(ga1 + ko, &As[pre][laofs1]);
      GLOAD(gb0 + ko, &Bs[pre][laofs0]);
      GLOAD(gb1 + ko, &Bs[pre][laofs1]);
      WAITV(8);                        // tile kt landed; kt+1,kt+2 in flight
    } else if (kt + 1 < NT1) {
      WAITV(4);
    } else {
      WAITV(0);
    }
    __builtin_amdgcn_s_barrier();      // #2: tile kt visible to all waves
    __builtin_amdgcn_sched_barrier(0); // fence: no ds_read hoists above
    bf16x8 af[4], bfr[4];
#pragma unroll
    for (int i = 0; i < 4; ++i) {
      af[i] = *(const bf16x8*)(&As[cur][(wm * 64 + i * 16 + lrow) * 32 + slot]);
      bfr[i] = *(const bf16x8*)(&Bs[cur][(wn * 64 + i * 16 + lrow) * 32 + slot]);
    }
    __builtin_amdgcn_s_setprio(1);
#pragma unroll
    for (int mt = 0; mt < 4; ++mt)
#pragma unroll
      for (int nt = 0; nt < 4; ++nt)
        acc[mt][nt] =
            __builtin_amdgcn_mfma_f32_16x16x32_bf16(bfr[nt], af[mt], acc[mt][nt], 0, 0, 0);
    __builtin_amdgcn_s_setprio(0);
    cur = (cur == 2) ? 0 : cur + 1;
    pre = (pre == 2) ? 0 : pre + 1;
  }

  // C^T epilogue: lane owns token gm = ..+lrow; 4 consecutive cols per (nt).
#pragma unroll
  for (int mt = 0; mt < 4; ++mt) {
    const int gm = m_base + wm * 64 + mt * 16 + lrow;
    if (gm < n_e) {
      bf16_t* orow = h1 + (size_t)(off + gm) * ID;
#pragma unroll
      for (int nt = 0; nt < 4; ++nt) {
        const int gi0 = n_base + wn * 64 + nt * 16 + quad * 4;
        const float4 bb = *(const float4*)(b1 + e * ID + gi0);
        const float bv[4] = {bb.x, bb.y, bb.z, bb.w};
        bf16_t o[4];
#pragma unroll
        for (int r = 0; r < 4; ++r) o[r] = (bf16_t)gelu_exact(acc[mt][nt][r] + bv[r]);
        *(uint2*)(orow + gi0) = *(uint2*)o;
      }
    }
  }
}

// gemm2: identical loop; epilogue stores y[pos] = row + b2 (bf16, no atomics).
__global__ __launch_bounds__(256, 3) void gemm2_kernel(
    const bf16_t* __restrict__ h1, const bf16_t* __restrict__ W2T, const float* __restrict__ b2,
    const int* __restrict__ counts, const int* __restrict__ offsets,
    const int* __restrict__ wl_e, const int* __restrict__ wl_m, const int* __restrict__ n_work,
    bf16_t* __restrict__ y) {
  const int widx = blockIdx.x;
  if (widx >= *n_work) return;
  const int e = wl_e[widx];
  const int m_base = wl_m[widx];
  const int n_e = counts[e];
  const int n_base = blockIdx.y * 128;
  const int off = offsets[e];

  __shared__ bf16_t As[3][128 * 32];
  __shared__ bf16_t Bs[3][128 * 32];

  const int tid = threadIdx.x;
  const int w = tid >> 6;
  const int lane = tid & 63;
  const int quad = lane >> 4;
  const int lrow = lane & 15;
  const int wm = w >> 1;
  const int wn = w & 1;

  const int srow = lane >> 2;
  const int kch = (((lane & 3) ^ ((lane >> 4) & 3)) * 8);
  int r0 = m_base + w * 32 + srow;
  int r1 = r0 + 16;
  if (r0 >= n_e) r0 = n_e - 1;
  if (r1 >= n_e) r1 = n_e - 1;
  const bf16_t* ga0 = h1 + (size_t)(off + r0) * ID + kch;
  const bf16_t* ga1 = h1 + (size_t)(off + r1) * ID + kch;
  const bf16_t* gb0 = W2T + ((size_t)e * HD + n_base + w * 32 + srow) * ID + kch;
  const bf16_t* gb1 = gb0 + (size_t)16 * ID;
  const int laofs0 = w * 1024 + lane * 8;
  const int laofs1 = laofs0 + 512;

  f32x4 acc[4][4];
#pragma unroll
  for (int mt = 0; mt < 4; ++mt)
#pragma unroll
    for (int nt = 0; nt < 4; ++nt)
#pragma unroll
      for (int r = 0; r < 4; ++r) acc[mt][nt][r] = 0.f;

#pragma unroll
  for (int p = 0; p < 2; ++p) {
    const size_t ko = (size_t)p * 32;
    GLOAD(ga0 + ko, &As[p][laofs0]);
    GLOAD(ga1 + ko, &As[p][laofs1]);
    GLOAD(gb0 + ko, &Bs[p][laofs0]);
    GLOAD(gb1 + ko, &Bs[p][laofs1]);
  }

  const int slot = (quad ^ ((lrow >> 2) & 3)) * 8;
  int cur = 0;
  int pre = 2;
#define NT2 (ID / 32)
  for (int kt = 0; kt < NT2; ++kt) {
    WAITL0();
    __builtin_amdgcn_s_barrier();
    if (kt + 2 < NT2) {
      const size_t ko = (size_t)(kt + 2) * 32;
      GLOAD(ga0 + ko, &As[pre][laofs0]);
      GLOAD(ga1 + ko, &As[pre][laofs1]);
      GLOAD(gb0 + ko, &Bs[pre][laofs0]);
      GLOAD(gb1 + ko, &Bs[pre][laofs1]);
      WAITV(8);
    } else if (kt + 1 < NT2) {
      WAITV(4);
    } else {
      WAITV(0);
    }
    __builtin_amdgcn_s_barrier();
    __builtin_amdgcn_sched_barrier(0);
    bf16x8 af[4], bfr[4];
#pragma unroll
    for (int i = 0; i < 4; ++i) {
      af[i] = *(const bf16x8*)(&As[cur][(wm * 64 + i * 16 + lrow) * 32 + slot]);
      bfr[i] = *(const bf16x8*)(&Bs[cur][(wn * 64 + i * 16 + lrow) * 32 + slot]);
    }
    __builtin_amdgcn_s_setprio(1);
#pragma unroll
    for (int mt = 0; mt < 4; ++mt)
#pragma unroll
      for (int nt = 0; nt < 4; ++nt)
        acc[mt][nt] =
            __builtin_amdgcn_mfma_f32_16x16x32_bf16(bfr[nt], af[mt], acc[mt][nt], 0, 0, 0);
    __builtin_amdgcn_s_setprio(0);
    cur = (cur == 2) ? 0 : cur + 1;
    pre = (pre == 2) ? 0 : pre + 1;
  }

#pragma unroll
  for (int mt = 0; mt < 4; ++mt) {
    const int gm = m_base + wm * 64 + mt * 16 + lrow;
    if (gm < n_e) {
      bf16_t* orow = y + (size_t)(off + gm) * HD;
#pragma unroll
      for (int nt = 0; nt < 4; ++nt) {
        const int gi0 = n_base + wn * 64 + nt * 16 + quad * 4;
        const float4 bb = *(const float4*)(b2 + e * HD + gi0);
        const float bv[4] = {bb.x, bb.y, bb.z, bb.w};
        bf16_t o[4];
#pragma unroll
        for (int r = 0; r < 4; ++r) o[r] = (bf16_t)(acc[mt][nt][r] + bv[r]);
        *(uint2*)(orow + gi0) = *(uint2*)o;
      }
    }
  }
}

// ---------------- combine: out[t] = w1*y[p1] + w2*y[p2] ----
__global__ __launch_bounds__(256) void combine_kernel(const bf16_t* __restrict__ y,
                                                      const int* __restrict__ pos_of,
                                                      const float* __restrict__ tok_w,
                                                      float* __restrict__ out) {
  const int gid = blockIdx.x * 256 + threadIdx.x;
  const int t = gid >> 7;             // 128 8-wide chunks per token row
  const int c8 = (gid & 127) * 8;
  const int p1 = pos_of[2 * t];
  const int p2 = pos_of[2 * t + 1];
  const float w1 = tok_w[2 * t];
  const float w2 = tok_w[2 * t + 1];
  const bf16x8 a = *(const bf16x8*)(y + (size_t)p1 * HD + c8);
  const bf16x8 b = *(const bf16x8*)(y + (size_t)p2 * HD + c8);
  float* op = out + (size_t)t * HD + c8;
  float ov[8];
#pragma unroll
  for (int j = 0; j < 8; ++j) ov[j] = w1 * (float)a[j] + w2 * (float)b[j];
  *(float4*)op = make_float4(ov[0], ov[1], ov[2], ov[3]);
  *(float4*)(op + 4) = make_float4(ov[4], ov[5], ov[6], ov[7]);
}

extern "C" void kernel_launch(void* const* d_in, const int* in_sizes, int n_in,
                              void* d_out, int out_size, void* d_ws, size_t ws_size,
                              hipStream_t stream) {
  const float* x = (const float*)d_in[0];
  const float* Wg = (const float*)d_in[1];
  const float* W1 = (const float*)d_in[2];
  const float* b1 = (const float*)d_in[3];
  const float* W2 = (const float*)d_in[4];
  const float* b2 = (const float*)d_in[5];
  float* out = (float*)d_out;
  char* ws = (char*)d_ws;

  int* counts = (int*)(ws + WS_COUNTS);
  int* offsets = (int*)(ws + WS_OFFSETS);
  int* bucket_tok = (int*)(ws + WS_BTOK);
  float* bucket_w = (float*)(ws + WS_BW);
  int* tok_e = (int*)(ws + WS_TE);
  float* tok_w = (float*)(ws + WS_TW);
  int* wl_e = (int*)(ws + WS_WL);
  int* wl_m = wl_e + MAXWL;
  int* n_work = wl_m + MAXWL;
  int* pos_of = (int*)(ws + WS_POS);
  int* rank_of = (int*)(ws + WS_RANK);
  int* blk_cnt = (int*)(ws + WS_BLKC);
  bf16_t* xb = (bf16_t*)(ws + WS_XB);
  bf16_t* h1 = (bf16_t*)(ws + WS_H1);
  bf16_t* w2t = (bf16_t*)(ws + WS_WT);
  bf16_t* w1t_y = (bf16_t*)(ws + WS_Y);  // W1T until gemm1 done; y afterwards

  prep_kernel<<<GB + 2 * TBLK, 256, 0, stream>>>(x, Wg, W1, W2, xb, w1t_y, w2t, tok_e, tok_w,
                                                 rank_of, blk_cnt);
  scatterscan_kernel<<<TOKS * 2 / 256, 256, 0, stream>>>(blk_cnt, tok_e, tok_w, rank_of, counts,
                                                         offsets, wl_e, wl_m, n_work, bucket_tok,
                                                         bucket_w, pos_of);
  gemm1_kernel<<<dim3(MAXWL, ID / 128), 256, 0, stream>>>(xb, w1t_y, b1, counts, offsets,
                                                          bucket_tok, wl_e, wl_m, n_work, h1);
  gemm2_kernel<<<dim3(MAXWL, HD / 128), 256, 0, stream>>>(h1, w2t, b2, counts, offsets, wl_e,
                                                          wl_m, n_work, w1t_y);
  combine_kernel<<<TOKS * HD / (256 * 8), 256, 0, stream>>>(w1t_y, pos_of, tok_w, out);
}

// Round 17
// 437.410 us; speedup vs baseline: 1.9290x; 1.0064x over previous
//
#include <hip/hip_runtime.h>
#include <math.h>

#define TOKS 8192
#define HD 1024
#define ID 2048
#define NE 8

typedef __bf16 bf16_t;
typedef __bf16 bf16x8 __attribute__((ext_vector_type(8)));
typedef float f32x4 __attribute__((ext_vector_type(4)));

// async global->LDS, 16 bytes per lane. LDS dest: wave-uniform base + lane*16.
#define GLOAD(gp, lp)                                                \
  __builtin_amdgcn_global_load_lds(                                  \
      (const __attribute__((address_space(1))) void*)(gp),           \
      (__attribute__((address_space(3))) void*)(lp), 16, 0, 0)

#define WAITV(N) asm volatile("s_waitcnt vmcnt(" #N ")" ::: "memory")
#define WAITL0() asm volatile("s_waitcnt lgkmcnt(0)" ::: "memory")

// branch-free erf-GELU (A&S 7.1.26, |eps|<=1.5e-7 — invisible under bf16 2^-9
// rounding). r11-verified: absmax unchanged vs libm erff.
__device__ __forceinline__ float gelu_exact(float v) {
  const float u = v * 0.70710678118654752f;
  const float a = fabsf(u);
  const float t = 1.f / (1.f + 0.3275911f * a);
  const float poly =
      t * (0.254829592f +
           t * (-0.284496736f +
                t * (1.421413741f + t * (-1.453152027f + t * 1.061405429f))));
  float er = 1.f - poly * __expf(-a * a);
  er = copysignf(er, u);
  return 0.5f * v * (1.f + er);
}

// ---------------- workspace layout (bytes) ----------------
#define WS_COUNTS 0
#define WS_OFFSETS 32
#define WS_BTOK 128
#define WS_BW (128 + 65536)
#define WS_TE (128 + 2 * 65536)
#define WS_TW (128 + 3 * 65536)
#define WS_WL 263168ull
#define WS_POS 274432ull                      // pos_of   [16384] int (64 KB)
#define WS_RANK 339968ull                     // rank_of  [16384] int (64 KB)
#define WS_BLKC 405504ull                     // blk_cnt  [1024][8] int (32 KB)
#define WS_XB 524288ull                       // bf16 x  [8192][1024]  = 16.78 MB
#define WS_H1 (WS_XB + 16777216ull)           // bf16 h1 [16384][2048] = 67.1 MB
#define WS_WT (WS_H1 + 67108864ull)           // bf16 W2T = 33.55 MB
#define WS_Y (WS_WT + 33554432ull)            // bf16: W1T until gemm1 done, then y
                                              //       [16384][1024] = 33.55 MB (end ~151.5 MB)
// Lifetime aliasing (r16-verified): W1T lives in the y region; y is first
// written by gemm2, by which time W1T (read only by gemm1) is dead.

#define MAXWL 144
#define BM 128      // m-tile (rows of token bucket)
#define GB 1024     // gate blocks; 8 tokens each (r12-verified parallelism:
                    // 4 blocks/CU of latency-hiding waves; r14's GB=256 left
                    // the gate path at 1 block/CU and straggling in prep)
#define TBLK 4096   // transpose blocks per weight tensor: (K/64)*(N/64)*NE

// ---------------- prep: fused gate + W1-transpose + W2-transpose ----------------
// Block-range dispatch: [0,GB) gate, [GB,GB+TBLK) W1->W1T, rest W2->W2T.
// 32 KB LDS union; all barriers block-uniform. Gate blocks first (longest).
__global__ __launch_bounds__(256) void prep_kernel(
    const float* __restrict__ x, const float* __restrict__ Wg, const float* __restrict__ W1,
    const float* __restrict__ W2, bf16_t* __restrict__ xb, bf16_t* __restrict__ w1t,
    bf16_t* __restrict__ w2t, int* __restrict__ tok_e, float* __restrict__ tok_w,
    int* __restrict__ rank_of, int* __restrict__ blk_cnt) {
  __shared__ __align__(16) float smem[HD * NE];  // 32 KB union
  __shared__ int cnt[NE];
  const int bid = blockIdx.x;
  const int tid = threadIdx.x;

  if (bid < GB) {
    // ---- gate path (r12-verified geometry: 8 tokens/block, 2 per wave) ----
#pragma unroll
    for (int i = 0; i < NE * HD / (256 * 4); ++i) {  // 8 float4 per thread
      const int k = i * 256 + tid;
      ((float4*)smem)[k] = ((const float4*)Wg)[k];
    }
    if (tid < NE) cnt[tid] = 0;
    __syncthreads();
    const int wv = tid >> 6;
    const int lane = tid & 63;
#pragma unroll
    for (int s = 0; s < 2; ++s) {
      const int t = bid * 8 + wv * 2 + s;
      const float* xrow = x + (size_t)t * HD;
      bf16_t* xbrow = xb + (size_t)t * HD;
      float acc[NE];
#pragma unroll
      for (int e = 0; e < NE; ++e) acc[e] = 0.f;
#pragma unroll
      for (int i = 0; i < 16; ++i) {
        const int h = i * 64 + lane;
        const float xv = xrow[h];
        xbrow[h] = (bf16_t)xv;  // fused convert
        const float4 w0 = *(const float4*)(smem + h * NE);
        const float4 w1 = *(const float4*)(smem + h * NE + 4);
        acc[0] += xv * w0.x;
        acc[1] += xv * w0.y;
        acc[2] += xv * w0.z;
        acc[3] += xv * w0.w;
        acc[4] += xv * w1.x;
        acc[5] += xv * w1.y;
        acc[6] += xv * w1.z;
        acc[7] += xv * w1.w;
      }
#pragma unroll
      for (int off = 32; off >= 1; off >>= 1) {
#pragma unroll
        for (int e = 0; e < NE; ++e) acc[e] += __shfl_xor(acc[e], off);
      }
      if (lane == 0) {
        int i1 = 0;
        float l1 = acc[0];
#pragma unroll
        for (int e = 1; e < NE; ++e)
          if (acc[e] > l1) { l1 = acc[e]; i1 = e; }
        int i2 = -1;
        float l2 = -3.4e38f;
#pragma unroll
        for (int e = 0; e < NE; ++e)
          if (e != i1 && acc[e] > l2) { l2 = acc[e]; i2 = e; }
        const float q = expf(l2 - l1);
        const float w1 = 1.f / (1.f + q);
        tok_e[2 * t] = i1;
        tok_e[2 * t + 1] = i2;
        tok_w[2 * t] = w1;
        tok_w[2 * t + 1] = q * w1;
        rank_of[2 * t] = atomicAdd(&cnt[i1], 1);
        rank_of[2 * t + 1] = atomicAdd(&cnt[i2], 1);
      }
    }
    __syncthreads();
    if (tid < NE) blk_cnt[bid * NE + tid] = cnt[tid];
  } else {
    // ---- transpose path (r11-verified body): src [E][K][N] f32 -> dst [E][N][K] bf16
    float(*tile)[65] = (float(*)[65])smem;  // 16.6 KB of the union
    const float* src;
    bf16_t* dst;
    int K, N, t;
    if (bid < GB + TBLK) {
      t = bid - GB;
      K = HD;
      N = ID;
      src = W1;
      dst = w1t;
    } else {
      t = bid - GB - TBLK;
      K = ID;
      N = HD;
      src = W2;
      dst = w2t;
    }
    const int ktiles = K / 64;
    const int ntiles = N / 64;
    const int kx = t % ktiles;
    const int ny = (t / ktiles) % ntiles;
    const int e = t / (ktiles * ntiles);
    const int k0 = kx * 64;
    const int n0 = ny * 64;
    const float* s = src + (size_t)e * K * N;
    bf16_t* d = dst + (size_t)e * K * N;
    const int c4 = (tid & 15) * 4;
    const int rr = tid >> 4;  // 0..15
#pragma unroll
    for (int p = 0; p < 4; ++p) {
      const int r = p * 16 + rr;
      const float4 v = *(const float4*)(s + (size_t)(k0 + r) * N + n0 + c4);
      tile[r][c4] = v.x;
      tile[r][c4 + 1] = v.y;
      tile[r][c4 + 2] = v.z;
      tile[r][c4 + 3] = v.w;
    }
    __syncthreads();
    const int kc = tid & 7;
    const int nb = tid >> 3;
#pragma unroll
    for (int p = 0; p < 2; ++p) {
      const int n = p * 32 + nb;
      bf16_t o[8];
#pragma unroll
      for (int j = 0; j < 8; ++j) o[j] = (bf16_t)tile[kc * 8 + j][n];
      *(uint4*)(d + (size_t)(n0 + n) * K + k0 + kc * 8) = *(uint4*)o;
    }
  }
}

// ---------------- scatterscan: scan (redundant per block, wave 0) + scatter ----
// r17: bb[1024][8] = 32 KB; scan = r12-verified 16-gate-blocks-per-lane form.
// 64 blocks x 256; block b scatters picks [b*256, b*256+256).
__global__ __launch_bounds__(256) void scatterscan_kernel(
    const int* __restrict__ blk_cnt, const int* __restrict__ tok_e,
    const float* __restrict__ tok_w, const int* __restrict__ rank_of,
    int* __restrict__ counts, int* __restrict__ offsets, int* __restrict__ wl_e,
    int* __restrict__ wl_m, int* __restrict__ n_work, int* __restrict__ bucket_tok,
    float* __restrict__ bucket_w, int* __restrict__ pos_of) {
  __shared__ int bb[GB][NE];  // 32 KB: per-gate-block base
  const int tid = threadIdx.x;
  if (tid < 64) {
    const int b = tid;  // lane b handles gate-blocks b*16 .. b*16+15
    int sum[NE], pre[NE], tot[NE];
#pragma unroll
    for (int e = 0; e < NE; ++e) {
      int s = 0;
      for (int j = 0; j < 16; ++j) s += blk_cnt[(b * 16 + j) * NE + e];
      sum[e] = s;
    }
#pragma unroll
    for (int e = 0; e < NE; ++e) {
      int v = sum[e];
#pragma unroll
      for (int off = 1; off < 64; off <<= 1) {
        const int u = __shfl_up(v, off);
        if (b >= off) v += u;
      }
      pre[e] = v - sum[e];
      tot[e] = __shfl(v, 63);
    }
    int off_[NE];
    int s = 0;
#pragma unroll
    for (int e = 0; e < NE; ++e) {
      off_[e] = s;
      s += tot[e];
    }
#pragma unroll
    for (int e = 0; e < NE; ++e) {
      int run = off_[e] + pre[e];
      for (int j = 0; j < 16; ++j) {
        bb[b * 16 + j][e] = run;
        run += blk_cnt[(b * 16 + j) * NE + e];
      }
    }
    if (blockIdx.x == 0 && b == 0) {
      int idx = 0;
      for (int e = 0; e < NE; ++e) {
        counts[e] = tot[e];
        offsets[e] = off_[e];
        for (int m = 0; m < tot[e] && idx < MAXWL; m += BM) {
          wl_e[idx] = e;
          wl_m[idx] = m;
          ++idx;
        }
      }
      *n_work = idx;
    }
  }
  __syncthreads();
  const int idx = blockIdx.x * 256 + tid;  // pick index
  const int e = tok_e[idx];
  const int g = idx >> 4;                  // 16 picks per gate-block
  const int pos = bb[g][e] + rank_of[idx];
  bucket_tok[pos] = idx >> 1;
  bucket_w[pos] = tok_w[idx];
  pos_of[idx] = pos;
}

// ---------------- expert GEMMs: 128x128 tile, 3-buffer counted-vmcnt ----------------
// r12/r15/r16-verified BEST (gemm1 127 us). Occupancy is a hill; 3 blocks/CU
// x 3-buffer is its top (r13 spill, r14 2-buf both slower).

__global__ __launch_bounds__(256, 3) void gemm1_kernel(
    const bf16_t* __restrict__ xb, const bf16_t* __restrict__ W1T, const float* __restrict__ b1,
    const int* __restrict__ counts, const int* __restrict__ offsets,
    const int* __restrict__ bucket_tok, const int* __restrict__ wl_e,
    const int* __restrict__ wl_m, const int* __restrict__ n_work, bf16_t* __restrict__ h1) {
  const int widx = blockIdx.x;
  if (widx >= *n_work) return;
  const int e = wl_e[widx];
  const int m_base = wl_m[widx];
  const int n_e = counts[e];
  const int n_base = blockIdx.y * 128;
  const int off = offsets[e];

  __shared__ bf16_t As[3][128 * 32];  // 8 KB each
  __shared__ bf16_t Bs[3][128 * 32];

  const int tid = threadIdx.x;
  const int w = tid >> 6;
  const int lane = tid & 63;
  const int quad = lane >> 4;
  const int lrow = lane & 15;
  const int wm = w >> 1;   // 64-row half
  const int wn = w & 1;    // 64-col half

  const int srow = lane >> 2;                        // 16 rows per GLOAD
  const int kch = (((lane & 3) ^ ((lane >> 4) & 3)) * 8);  // pre-swizzled source chunk
  int r0 = m_base + w * 32 + srow;
  int r1 = r0 + 16;
  if (r0 >= n_e) r0 = n_e - 1;
  if (r1 >= n_e) r1 = n_e - 1;
  const bf16_t* ga0 = xb + (size_t)bucket_tok[off + r0] * HD + kch;
  const bf16_t* ga1 = xb + (size_t)bucket_tok[off + r1] * HD + kch;
  const bf16_t* gb0 = W1T + ((size_t)e * ID + n_base + w * 32 + srow) * HD + kch;
  const bf16_t* gb1 = gb0 + (size_t)16 * HD;
  const int laofs0 = w * 1024 + lane * 8;  // rows w*32.. in [128][32]
  const int laofs1 = laofs0 + 512;         // +16 rows

  f32x4 acc[4][4];
#pragma unroll
  for (int mt = 0; mt < 4; ++mt)
#pragma unroll
    for (int nt = 0; nt < 4; ++nt)
#pragma unroll
      for (int r = 0; r < 4; ++r) acc[mt][nt][r] = 0.f;

  // prologue: stage tiles 0 and 1 (8 outstanding GLOADs/wave)
#pragma unroll
  for (int p = 0; p < 2; ++p) {
    const size_t ko = (size_t)p * 32;
    GLOAD(ga0 + ko, &As[p][laofs0]);
    GLOAD(ga1 + ko, &As[p][laofs1]);
    GLOAD(gb0 + ko, &Bs[p][laofs0]);
    GLOAD(gb1 + ko, &Bs[p][laofs1]);
  }

  const int slot = (quad ^ ((lrow >> 2) & 3)) * 8;
  int cur = 0;        // kt % 3, carried (no div in loop)
  int pre = 2;        // (kt+2) % 3, carried
#define NT1 (HD / 32)
  for (int kt = 0; kt < NT1; ++kt) {
    WAITL0();                          // prior iter's ds_reads done (per-wave)
    __builtin_amdgcn_s_barrier();      // #1: buf[(kt+2)%3] free to overwrite
    if (kt + 2 < NT1) {
      const size_t ko = (size_t)(kt + 2) * 32;
      GLOAD(ga0 + ko, &As[pre][laofs0]);
      GLOAD(ga1 + ko, &As[pre][laofs1]);
      GLOAD(gb0 + ko, &Bs[pre][laofs0]);
      GLOAD(gb1 + ko, &Bs[pre][laofs1]);
      WAITV(8);                        // tile kt landed; kt+1,kt+2 in flight
    } else if (kt + 1 < NT1) {
      WAITV(4);
    } else {
      WAITV(0);
    }
    __builtin_amdgcn_s_barrier();      // #2: tile kt visible to all waves
    __builtin_amdgcn_sched_barrier(0); // fence: no ds_read hoists above
    bf16x8 af[4], bfr[4];
#pragma unroll
    for (int i = 0; i < 4; ++i) {
      af[i] = *(const bf16x8*)(&As[cur][(wm * 64 + i * 16 + lrow) * 32 + slot]);
      bfr[i] = *(const bf16x8*)(&Bs[cur][(wn * 64 + i * 16 + lrow) * 32 + slot]);
    }
    __builtin_amdgcn_s_setprio(1);
#pragma unroll
    for (int mt = 0; mt < 4; ++mt)
#pragma unroll
      for (int nt = 0; nt < 4; ++nt)
        acc[mt][nt] =
            __builtin_amdgcn_mfma_f32_16x16x32_bf16(bfr[nt], af[mt], acc[mt][nt], 0, 0, 0);
    __builtin_amdgcn_s_setprio(0);
    cur = (cur == 2) ? 0 : cur + 1;
    pre = (pre == 2) ? 0 : pre + 1;
  }

  // C^T epilogue: lane owns token gm = ..+lrow; 4 consecutive cols per (nt).
#pragma unroll
  for (int mt = 0; mt < 4; ++mt) {
    const int gm = m_base + wm * 64 + mt * 16 + lrow;
    if (gm < n_e) {
      bf16_t* orow = h1 + (size_t)(off + gm) * ID;
#pragma unroll
      for (int nt = 0; nt < 4; ++nt) {
        const int gi0 = n_base + wn * 64 + nt * 16 + quad * 4;
        const float4 bb = *(const float4*)(b1 + e * ID + gi0);
        const float bv[4] = {bb.x, bb.y, bb.z, bb.w};
        bf16_t o[4];
#pragma unroll
        for (int r = 0; r < 4; ++r) o[r] = (bf16_t)gelu_exact(acc[mt][nt][r] + bv[r]);
        *(uint2*)(orow + gi0) = *(uint2*)o;
      }
    }
  }
}

// gemm2: identical loop; epilogue stores y[pos] = row + b2 (bf16, no atomics).
__global__ __launch_bounds__(256, 3) void gemm2_kernel(
    const bf16_t* __restrict__ h1, const bf16_t* __restrict__ W2T, const float* __restrict__ b2,
    const int* __restrict__ counts, const int* __restrict__ offsets,
    const int* __restrict__ wl_e, const int* __restrict__ wl_m, const int* __restrict__ n_work,
    bf16_t* __restrict__ y) {
  const int widx = blockIdx.x;
  if (widx >= *n_work) return;
  const int e = wl_e[widx];
  const int m_base = wl_m[widx];
  const int n_e = counts[e];
  const int n_base = blockIdx.y * 128;
  const int off = offsets[e];

  __shared__ bf16_t As[3][128 * 32];
  __shared__ bf16_t Bs[3][128 * 32];

  const int tid = threadIdx.x;
  const int w = tid >> 6;
  const int lane = tid & 63;
  const int quad = lane >> 4;
  const int lrow = lane & 15;
  const int wm = w >> 1;
  const int wn = w & 1;

  const int srow = lane >> 2;
  const int kch = (((lane & 3) ^ ((lane >> 4) & 3)) * 8);
  int r0 = m_base + w * 32 + srow;
  int r1 = r0 + 16;
  if (r0 >= n_e) r0 = n_e - 1;
  if (r1 >= n_e) r1 = n_e - 1;
  const bf16_t* ga0 = h1 + (size_t)(off + r0) * ID + kch;
  const bf16_t* ga1 = h1 + (size_t)(off + r1) * ID + kch;
  const bf16_t* gb0 = W2T + ((size_t)e * HD + n_base + w * 32 + srow) * ID + kch;
  const bf16_t* gb1 = gb0 + (size_t)16 * ID;
  const int laofs0 = w * 1024 + lane * 8;
  const int laofs1 = laofs0 + 512;

  f32x4 acc[4][4];
#pragma unroll
  for (int mt = 0; mt < 4; ++mt)
#pragma unroll
    for (int nt = 0; nt < 4; ++nt)
#pragma unroll
      for (int r = 0; r < 4; ++r) acc[mt][nt][r] = 0.f;

#pragma unroll
  for (int p = 0; p < 2; ++p) {
    const size_t ko = (size_t)p * 32;
    GLOAD(ga0 + ko, &As[p][laofs0]);
    GLOAD(ga1 + ko, &As[p][laofs1]);
    GLOAD(gb0 + ko, &Bs[p][laofs0]);
    GLOAD(gb1 + ko, &Bs[p][laofs1]);
  }

  const int slot = (quad ^ ((lrow >> 2) & 3)) * 8;
  int cur = 0;
  int pre = 2;
#define NT2 (ID / 32)
  for (int kt = 0; kt < NT2; ++kt) {
    WAITL0();
    __builtin_amdgcn_s_barrier();
    if (kt + 2 < NT2) {
      const size_t ko = (size_t)(kt + 2) * 32;
      GLOAD(ga0 + ko, &As[pre][laofs0]);
      GLOAD(ga1 + ko, &As[pre][laofs1]);
      GLOAD(gb0 + ko, &Bs[pre][laofs0]);
      GLOAD(gb1 + ko, &Bs[pre][laofs1]);
      WAITV(8);
    } else if (kt + 1 < NT2) {
      WAITV(4);
    } else {
      WAITV(0);
    }
    __builtin_amdgcn_s_barrier();
    __builtin_amdgcn_sched_barrier(0);
    bf16x8 af[4], bfr[4];
#pragma unroll
    for (int i = 0; i < 4; ++i) {
      af[i] = *(const bf16x8*)(&As[cur][(wm * 64 + i * 16 + lrow) * 32 + slot]);
      bfr[i] = *(const bf16x8*)(&Bs[cur][(wn * 64 + i * 16 + lrow) * 32 + slot]);
    }
    __builtin_amdgcn_s_setprio(1);
#pragma unroll
    for (int mt = 0; mt < 4; ++mt)
#pragma unroll
      for (int nt = 0; nt < 4; ++nt)
        acc[mt][nt] =
            __builtin_amdgcn_mfma_f32_16x16x32_bf16(bfr[nt], af[mt], acc[mt][nt], 0, 0, 0);
    __builtin_amdgcn_s_setprio(0);
    cur = (cur == 2) ? 0 : cur + 1;
    pre = (pre == 2) ? 0 : pre + 1;
  }

#pragma unroll
  for (int mt = 0; mt < 4; ++mt) {
    const int gm = m_base + wm * 64 + mt * 16 + lrow;
    if (gm < n_e) {
      bf16_t* orow = y + (size_t)(off + gm) * HD;
#pragma unroll
      for (int nt = 0; nt < 4; ++nt) {
        const int gi0 = n_base + wn * 64 + nt * 16 + quad * 4;
        const float4 bb = *(const float4*)(b2 + e * HD + gi0);
        const float bv[4] = {bb.x, bb.y, bb.z, bb.w};
        bf16_t o[4];
#pragma unroll
        for (int r = 0; r < 4; ++r) o[r] = (bf16_t)(acc[mt][nt][r] + bv[r]);
        *(uint2*)(orow + gi0) = *(uint2*)o;
      }
    }
  }
}

// ---------------- combine: out[t] = w1*y[p1] + w2*y[p2] ----
__global__ __launch_bounds__(256) void combine_kernel(const bf16_t* __restrict__ y,
                                                      const int* __restrict__ pos_of,
                                                      const float* __restrict__ tok_w,
                                                      float* __restrict__ out) {
  const int gid = blockIdx.x * 256 + threadIdx.x;
  const int t = gid >> 7;             // 128 8-wide chunks per token row
  const int c8 = (gid & 127) * 8;
  const int p1 = pos_of[2 * t];
  const int p2 = pos_of[2 * t + 1];
  const float w1 = tok_w[2 * t];
  const float w2 = tok_w[2 * t + 1];
  const bf16x8 a = *(const bf16x8*)(y + (size_t)p1 * HD + c8);
  const bf16x8 b = *(const bf16x8*)(y + (size_t)p2 * HD + c8);
  float* op = out + (size_t)t * HD + c8;
  float ov[8];
#pragma unroll
  for (int j = 0; j < 8; ++j) ov[j] = w1 * (float)a[j] + w2 * (float)b[j];
  *(float4*)op = make_float4(ov[0], ov[1], ov[2], ov[3]);
  *(float4*)(op + 4) = make_float4(ov[4], ov[5], ov[6], ov[7]);
}

extern "C" void kernel_launch(void* const* d_in, const int* in_sizes, int n_in,
                              void* d_out, int out_size, void* d_ws, size_t ws_size,
                              hipStream_t stream) {
  const float* x = (const float*)d_in[0];
  const float* Wg = (const float*)d_in[1];
  const float* W1 = (const float*)d_in[2];
  const float* b1 = (const float*)d_in[3];
  const float* W2 = (const float*)d_in[4];
  const float* b2 = (const float*)d_in[5];
  float* out = (float*)d_out;
  char* ws = (char*)d_ws;

  int* counts = (int*)(ws + WS_COUNTS);
  int* offsets = (int*)(ws + WS_OFFSETS);
  int* bucket_tok = (int*)(ws + WS_BTOK);
  float* bucket_w = (float*)(ws + WS_BW);
  int* tok_e = (int*)(ws + WS_TE);
  float* tok_w = (float*)(ws + WS_TW);
  int* wl_e = (int*)(ws + WS_WL);
  int* wl_m = wl_e + MAXWL;
  int* n_work = wl_m + MAXWL;
  int* pos_of = (int*)(ws + WS_POS);
  int* rank_of = (int*)(ws + WS_RANK);
  int* blk_cnt = (int*)(ws + WS_BLKC);
  bf16_t* xb = (bf16_t*)(ws + WS_XB);
  bf16_t* h1 = (bf16_t*)(ws + WS_H1);
  bf16_t* w2t = (bf16_t*)(ws + WS_WT);
  bf16_t* w1t_y = (bf16_t*)(ws + WS_Y);  // W1T until gemm1 done; y afterwards

  prep_kernel<<<GB + 2 * TBLK, 256, 0, stream>>>(x, Wg, W1, W2, xb, w1t_y, w2t, tok_e, tok_w,
                                                 rank_of, blk_cnt);
  scatterscan_kernel<<<TOKS * 2 / 256, 256, 0, stream>>>(blk_cnt, tok_e, tok_w, rank_of, counts,
                                                         offsets, wl_e, wl_m, n_work, bucket_tok,
                                                         bucket_w, pos_of);
  gemm1_kernel<<<dim3(MAXWL, ID / 128), 256, 0, stream>>>(xb, w1t_y, b1, counts, offsets,
                                                          bucket_tok, wl_e, wl_m, n_work, h1);
  gemm2_kernel<<<dim3(MAXWL, HD / 128), 256, 0, stream>>>(h1, w2t, b2, counts, offsets, wl_e,
                                                          wl_m, n_work, w1t_y);
  combine_kernel<<<TOKS * HD / (256 * 8), 256, 0, stream>>>(w1t_y, pos_of, tok_w, out);
}